// Round 1
// baseline (17910.982 us; speedup 1.0000x reference)
//
#include <hip/hip_runtime.h>
#include <math.h>

#define T_  1024
#define D_  512
#define H_  8
#define DK_ 64
#define FF_ 2048
#define BSZ 8
#define M_  (BSZ * T_)   // 8192 rows

// ======================= generic tiled f32 GEMM =======================
#define BM 64
#define BN 64
#define BK 16

__global__ void __launch_bounds__(256) gemm_bias(
    const float* __restrict__ A, const float* __restrict__ B,
    const float* __restrict__ bias, float* __restrict__ C,
    int M, int N, int K, int relu)
{
    __shared__ float As[BK][BM + 4];
    __shared__ float Bs[BK][BN + 4];
    int tid = threadIdx.x;
    int tx = tid & 15, ty = tid >> 4;
    int n0 = blockIdx.x * BN;
    int m0 = blockIdx.y * BM;
    int ar = tid >> 2, ak = (tid & 3) * 4;   // A tile: 64 rows x 16 k
    int br = tid >> 4, bc = (tid & 15) * 4;  // B tile: 16 k x 64 cols

    float acc[4][4] = {};
    for (int k0 = 0; k0 < K; k0 += BK) {
        float4 av = *(const float4*)(A + (size_t)(m0 + ar) * K + (k0 + ak));
        As[ak + 0][ar] = av.x; As[ak + 1][ar] = av.y;
        As[ak + 2][ar] = av.z; As[ak + 3][ar] = av.w;
        float4 bv = *(const float4*)(B + (size_t)(k0 + br) * N + (n0 + bc));
        *(float4*)&Bs[br][bc] = bv;
        __syncthreads();
#pragma unroll
        for (int kk = 0; kk < BK; ++kk) {
            float4 a = *(const float4*)&As[kk][ty * 4];
            float4 b = *(const float4*)&Bs[kk][tx * 4];
            acc[0][0] += a.x * b.x; acc[0][1] += a.x * b.y; acc[0][2] += a.x * b.z; acc[0][3] += a.x * b.w;
            acc[1][0] += a.y * b.x; acc[1][1] += a.y * b.y; acc[1][2] += a.y * b.z; acc[1][3] += a.y * b.w;
            acc[2][0] += a.z * b.x; acc[2][1] += a.z * b.y; acc[2][2] += a.z * b.z; acc[2][3] += a.z * b.w;
            acc[3][0] += a.w * b.x; acc[3][1] += a.w * b.y; acc[3][2] += a.w * b.z; acc[3][3] += a.w * b.w;
        }
        __syncthreads();
    }
    float4 b4 = *(const float4*)(bias + n0 + tx * 4);
#pragma unroll
    for (int r = 0; r < 4; ++r) {
        float4 v;
        v.x = acc[r][0] + b4.x; v.y = acc[r][1] + b4.y;
        v.z = acc[r][2] + b4.z; v.w = acc[r][3] + b4.w;
        if (relu) {
            v.x = fmaxf(v.x, 0.f); v.y = fmaxf(v.y, 0.f);
            v.z = fmaxf(v.z, 0.f); v.w = fmaxf(v.w, 0.f);
        }
        *(float4*)(C + (size_t)(m0 + ty * 4 + r) * N + n0 + tx * 4) = v;
    }
}

// ======================= causal conv1d as 5 shifted GEMMs =======================
// trend[m][o] = sum_{ks=0..4} sum_i X[m+ks-4][i] * W5[ks][i][o]   (zero when t+ks-4<0)
__global__ void __launch_bounds__(256) conv_gemm(
    const float* __restrict__ X, const float* __restrict__ W5, float* __restrict__ C)
{
    __shared__ float As[BK][BM + 4];
    __shared__ float Bs[BK][BN + 4];
    int tid = threadIdx.x;
    int tx = tid & 15, ty = tid >> 4;
    int n0 = blockIdx.x * BN;
    int m0 = blockIdx.y * BM;
    int ar = tid >> 2, ak = (tid & 3) * 4;
    int br = tid >> 4, bc = (tid & 15) * 4;

    int m = m0 + ar;
    int t = m & (T_ - 1);
    float acc[4][4] = {};
    for (int ks = 0; ks < 5; ++ks) {
        int shift = ks - 4;
        bool valid = (t + shift) >= 0;
        const float* Bp = W5 + (size_t)ks * D_ * D_;
        const float* Arow = X + (size_t)(valid ? (m + shift) : 0) * D_;
        for (int k0 = 0; k0 < D_; k0 += BK) {
            float4 av = valid ? *(const float4*)(Arow + k0 + ak) : make_float4(0.f, 0.f, 0.f, 0.f);
            As[ak + 0][ar] = av.x; As[ak + 1][ar] = av.y;
            As[ak + 2][ar] = av.z; As[ak + 3][ar] = av.w;
            float4 bv = *(const float4*)(Bp + (size_t)(k0 + br) * D_ + (n0 + bc));
            *(float4*)&Bs[br][bc] = bv;
            __syncthreads();
#pragma unroll
            for (int kk = 0; kk < BK; ++kk) {
                float4 a = *(const float4*)&As[kk][ty * 4];
                float4 b = *(const float4*)&Bs[kk][tx * 4];
                acc[0][0] += a.x * b.x; acc[0][1] += a.x * b.y; acc[0][2] += a.x * b.z; acc[0][3] += a.x * b.w;
                acc[1][0] += a.y * b.x; acc[1][1] += a.y * b.y; acc[1][2] += a.y * b.z; acc[1][3] += a.y * b.w;
                acc[2][0] += a.z * b.x; acc[2][1] += a.z * b.y; acc[2][2] += a.z * b.z; acc[2][3] += a.z * b.w;
                acc[3][0] += a.w * b.x; acc[3][1] += a.w * b.y; acc[3][2] += a.w * b.z; acc[3][3] += a.w * b.w;
            }
            __syncthreads();
        }
    }
#pragma unroll
    for (int r = 0; r < 4; ++r) {
        float4 v;
        v.x = acc[r][0]; v.y = acc[r][1]; v.z = acc[r][2]; v.w = acc[r][3];
        *(float4*)(C + (size_t)(m0 + ty * 4 + r) * D_ + n0 + tx * 4) = v;
    }
}

// repack conv_w (O,I,KS) -> W5[ks][i][o]
__global__ void repack_w(const float* __restrict__ cw, float* __restrict__ W5)
{
    int idx = blockIdx.x * 256 + threadIdx.x;
    if (idx >= 5 * D_ * D_) return;
    int k = idx / (D_ * D_);
    int rem = idx - k * D_ * D_;
    int ii = rem / D_;
    int o = rem - ii * D_;
    W5[idx] = cw[((size_t)o * D_ + ii) * 5 + k];
}

// ======================= smooth pointwise + LayerNorm (eps=1e-12) =======================
__global__ void __launch_bounds__(256) smooth_ln(
    const float* __restrict__ x, const float* __restrict__ trend,
    const float* __restrict__ conv_b, const float* __restrict__ sqrt_beta,
    const float* __restrict__ g, const float* __restrict__ bb,
    float* __restrict__ out)
{
    __shared__ float s_red[8];
    int row = blockIdx.x, tid = threadIdx.x;
    int lane = tid & 63, wid = tid >> 6;
    float2 xv = ((const float2*)(x + (size_t)row * D_))[tid];
    float2 tv = ((const float2*)(trend + (size_t)row * D_))[tid];
    float2 cb = ((const float2*)conv_b)[tid];
    float2 sb = ((const float2*)sqrt_beta)[tid];
    float t0 = tv.x + cb.x, t1 = tv.y + cb.y;
    float v0 = t0 + sb.x * sb.x * (xv.x - t0) + xv.x;
    float v1 = t1 + sb.y * sb.y * (xv.y - t1) + xv.y;
    float s = v0 + v1, sq = v0 * v0 + v1 * v1;
    for (int o = 32; o > 0; o >>= 1) { s += __shfl_xor(s, o, 64); sq += __shfl_xor(sq, o, 64); }
    if (lane == 0) { s_red[wid] = s; s_red[4 + wid] = sq; }
    __syncthreads();
    s = s_red[0] + s_red[1] + s_red[2] + s_red[3];
    sq = s_red[4] + s_red[5] + s_red[6] + s_red[7];
    float mean = s * (1.f / D_);
    float var = sq * (1.f / D_) - mean * mean;
    if (var < 0.f) var = 0.f;
    float rstd = rsqrtf(var + 1e-12f);
    float2 gv = ((const float2*)g)[tid];
    float2 bv = ((const float2*)bb)[tid];
    float2 o2;
    o2.x = gv.x * (v0 - mean) * rstd + bv.x;
    o2.y = gv.y * (v1 - mean) * rstd + bv.y;
    ((float2*)(out + (size_t)row * D_))[tid] = o2;
}

// ======================= residual add + LayerNorm =======================
__global__ void __launch_bounds__(256) add_ln(
    const float* __restrict__ a, const float* __restrict__ c,
    const float* __restrict__ g, const float* __restrict__ bb,
    float* __restrict__ out, float eps)
{
    __shared__ float s_red[8];
    int row = blockIdx.x, tid = threadIdx.x;
    int lane = tid & 63, wid = tid >> 6;
    float2 av = ((const float2*)(a + (size_t)row * D_))[tid];
    float2 cv = ((const float2*)(c + (size_t)row * D_))[tid];
    float v0 = av.x + cv.x;
    float v1 = av.y + cv.y;
    float s = v0 + v1, sq = v0 * v0 + v1 * v1;
    for (int o = 32; o > 0; o >>= 1) { s += __shfl_xor(s, o, 64); sq += __shfl_xor(sq, o, 64); }
    if (lane == 0) { s_red[wid] = s; s_red[4 + wid] = sq; }
    __syncthreads();
    s = s_red[0] + s_red[1] + s_red[2] + s_red[3];
    sq = s_red[4] + s_red[5] + s_red[6] + s_red[7];
    float mean = s * (1.f / D_);
    float var = sq * (1.f / D_) - mean * mean;
    if (var < 0.f) var = 0.f;
    float rstd = rsqrtf(var + eps);
    float2 gv = ((const float2*)g)[tid];
    float2 bv = ((const float2*)bb)[tid];
    float2 o2;
    o2.x = gv.x * (v0 - mean) * rstd + bv.x;
    o2.y = gv.y * (v1 - mean) * rstd + bv.y;
    ((float2*)(out + (size_t)row * D_))[tid] = o2;
}

// ======================= fused decay attention, one block per (b,h,i) =======================
// Q,K,V,Out are [B*T, D] row-major; head h occupies cols [h*64, h*64+64).
// mtype=1: valid k<=i.  mtype=0: valid k<=i-1 and zero_pad row 0.
__global__ void __launch_bounds__(256) attn_kernel(
    const float* __restrict__ Qm, const float* __restrict__ Km,
    const float* __restrict__ Vm, const float* __restrict__ gam_l,
    float* __restrict__ Out, int mtype)
{
    __shared__ float s_q[DK_];
    __shared__ float s_p[T_];
    __shared__ float s_red[8];
    __shared__ float s_part[4][DK_];

    int bid = blockIdx.x;
    int i  = bid & (T_ - 1);
    int bh = bid >> 10;
    int h  = bh & (H_ - 1);
    int b  = bh >> 3;
    int tid = threadIdx.x;
    int lane = tid & 63, wid = tid >> 6;

    size_t baserow = (size_t)(b * T_ + i) * D_ + h * DK_;
    float* orow = Out + baserow;
    int kmax = (mtype == 0) ? (i - 1) : i;
    if (kmax < 0) {                       // only mtype==0, i==0; zero_pad zeroes it anyway
        if (tid < DK_) orow[tid] = 0.f;
        return;
    }

    if (tid < DK_) s_q[tid] = Qm[baserow + tid];
    __syncthreads();

    // ---- raw scores, 4 contiguous k per thread ----
    int k0 = tid * 4;
    float sc[4];
#pragma unroll
    for (int j = 0; j < 4; ++j) {
        int k = k0 + j;
        float dot = -1e30f;
        if (k <= kmax) {
            const float4* kr = (const float4*)(Km + (size_t)(b * T_ + k) * D_ + h * DK_);
            const float4* q4 = (const float4*)s_q;
            float d0 = 0.f;
#pragma unroll
            for (int dd = 0; dd < 16; ++dd) {
                float4 kv = kr[dd], qv = q4[dd];
                d0 += kv.x * qv.x + kv.y * qv.y + kv.z * qv.z + kv.w * qv.w;
            }
            dot = d0 * 0.125f;   // 1/sqrt(64)
        }
        sc[j] = dot;
    }

    // ---- softmax #1 (masked) -> s_ ----
    float mx = fmaxf(fmaxf(sc[0], sc[1]), fmaxf(sc[2], sc[3]));
    for (int o = 32; o > 0; o >>= 1) mx = fmaxf(mx, __shfl_xor(mx, o, 64));
    if (lane == 0) s_red[wid] = mx;
    __syncthreads();
    mx = fmaxf(fmaxf(s_red[0], s_red[1]), fmaxf(s_red[2], s_red[3]));
    __syncthreads();

    float p[4]; float ls = 0.f;
#pragma unroll
    for (int j = 0; j < 4; ++j) {
        p[j] = (k0 + j <= kmax) ? __expf(sc[j] - mx) : 0.f;
        ls += p[j];
    }
    float ssum = ls;
    for (int o = 32; o > 0; o >>= 1) ssum += __shfl_xor(ssum, o, 64);
    if (lane == 0) s_red[wid] = ssum;
    __syncthreads();
    float denom = s_red[0] + s_red[1] + s_red[2] + s_red[3];
    __syncthreads();
    float inv1 = 1.f / denom;
#pragma unroll
    for (int j = 0; j < 4; ++j) p[j] *= inv1;

    // ---- inclusive cumsum of s_ over k ----
    float tsum = p[0] + p[1] + p[2] + p[3];
    float incl = tsum;
    for (int o = 1; o < 64; o <<= 1) {
        float y = __shfl_up(incl, o, 64);
        if (lane >= o) incl += y;
    }
    if (lane == 63) s_red[wid] = incl;
    __syncthreads();
    float woff = 0.f;
    for (int w = 0; w < wid; ++w) woff += s_red[w];
    float total = s_red[0] + s_red[1] + s_red[2] + s_red[3];
    __syncthreads();
    float run = woff + incl - tsum;   // exclusive prefix at this thread's first k

    // ---- distance effect + rescored ----
    float gp = gam_l[h];
    float gam = -log1pf(__expf(gp));    // -softplus(gamma)
#pragma unroll
    for (int j = 0; j < 4; ++j) {
        int k = k0 + j;
        run += p[j];
        float rem = total - run;
        if (rem < 0.f) rem = 0.f;
        float pos = fabsf((float)(k - i));
        float dist = sqrtf(rem * pos);
        float eff = __expf(dist * gam);
        eff = fminf(fmaxf(eff, 1e-5f), 1e5f);
        sc[j] = (k <= kmax) ? sc[j] * eff : -1e30f;
    }

    // ---- softmax #2 ----
    mx = fmaxf(fmaxf(sc[0], sc[1]), fmaxf(sc[2], sc[3]));
    for (int o = 32; o > 0; o >>= 1) mx = fmaxf(mx, __shfl_xor(mx, o, 64));
    if (lane == 0) s_red[wid] = mx;
    __syncthreads();
    mx = fmaxf(fmaxf(s_red[0], s_red[1]), fmaxf(s_red[2], s_red[3]));
    __syncthreads();
    ls = 0.f;
#pragma unroll
    for (int j = 0; j < 4; ++j) {
        p[j] = (k0 + j <= kmax) ? __expf(sc[j] - mx) : 0.f;
        ls += p[j];
    }
    ssum = ls;
    for (int o = 32; o > 0; o >>= 1) ssum += __shfl_xor(ssum, o, 64);
    if (lane == 0) s_red[wid] = ssum;
    __syncthreads();
    float denom2 = s_red[0] + s_red[1] + s_red[2] + s_red[3];
    float inv2 = 1.f / denom2;
#pragma unroll
    for (int j = 0; j < 4; ++j) s_p[k0 + j] = p[j] * inv2;
    __syncthreads();

    // ---- PV: lanes over d, 4 chunks of 256 k ----
    int d = tid & 63, ch = tid >> 6;
    int kb = ch * 256;
    int ke = min(kb + 256, kmax + 1);
    float acc = 0.f;
    const float* Vp = Vm + (size_t)(b * T_) * D_ + h * DK_ + d;
    for (int k = kb; k < ke; ++k) acc += s_p[k] * Vp[(size_t)k * D_];
    s_part[ch][d] = acc;
    __syncthreads();
    if (tid < DK_)
        orow[tid] = s_part[0][tid] + s_part[1][tid] + s_part[2][tid] + s_part[3][tid];
}

// ======================= launch =======================
extern "C" void kernel_launch(void* const* d_in, const int* in_sizes, int n_in,
                              void* d_out, int out_size, void* d_ws, size_t ws_size,
                              hipStream_t stream)
{
    const float* q_embed   = (const float*)d_in[0];
    const float* qa_embed  = (const float*)d_in[1];
    const float* conv_w    = (const float*)d_in[3];
    const float* conv_b    = (const float*)d_in[4];
    const float* sqrt_beta = (const float*)d_in[5];
    const float* sm_g      = (const float*)d_in[6];
    const float* sm_b      = (const float*)d_in[7];
    const float* k_w       = (const float*)d_in[8];
    const float* k_b       = (const float*)d_in[9];
    const float* v_w       = (const float*)d_in[10];
    const float* v_b       = (const float*)d_in[11];
    const float* out_w     = (const float*)d_in[12];
    const float* out_b     = (const float*)d_in[13];
    const float* gammas    = (const float*)d_in[14];
    const float* ln1_g     = (const float*)d_in[15];
    const float* ln1_b     = (const float*)d_in[16];
    const float* ff1_w     = (const float*)d_in[17];
    const float* ff1_b     = (const float*)d_in[18];
    const float* ff2_w     = (const float*)d_in[19];
    const float* ff2_b     = (const float*)d_in[20];
    const float* ln2_g     = (const float*)d_in[21];
    const float* ln2_b     = (const float*)d_in[22];

    const size_t NT = (size_t)M_ * D_;   // 4,194,304 floats
    float* X  = (float*)d_out;           // x-stream lives in d_out
    float* ws = (float*)d_ws;
    float* Y  = ws;                      // y-stream
    float* Qb = ws + NT;                 // q (== k) projection
    float* Vb = ws + 2 * NT;             // v projection
    float* Fb = ws + 3 * NT;             // trend / attn-concat / ffn-out
    float* Gb = ws + 4 * NT;             // q2 / ffn-hidden (8192 x 2048)
    float* W5 = ws + 4 * NT + (size_t)M_ * FF_;  // repacked conv weights (5*512*512)

    dim3 blk(256);
    dim3 gD(D_ / BN, M_ / BM);
    dim3 gF(FF_ / BN, M_ / BM);

    repack_w<<<(5 * D_ * D_ + 255) / 256, blk, 0, stream>>>(conv_w, W5);

    // smooth(x) and smooth(y)
    conv_gemm<<<gD, blk, 0, stream>>>(q_embed, W5, Fb);
    smooth_ln<<<M_, blk, 0, stream>>>(q_embed, Fb, conv_b, sqrt_beta, sm_g, sm_b, X);
    conv_gemm<<<gD, blk, 0, stream>>>(qa_embed, W5, Fb);
    smooth_ln<<<M_, blk, 0, stream>>>(qa_embed, Fb, conv_b, sqrt_beta, sm_g, sm_b, Y);

    auto layer = [&](int l, int mtype, float* io, const float* vin, bool ffn) {
        const float* kwl = k_w + (size_t)l * D_ * D_;
        const float* kbl = k_b + (size_t)l * D_;
        const float* vwl = v_w + (size_t)l * D_ * D_;
        const float* vbl = v_b + (size_t)l * D_;
        const float* owl = out_w + (size_t)l * D_ * D_;
        const float* obl = out_b + (size_t)l * D_;
        // q == k (kq_same and q_in==k_in in every call): one projection
        gemm_bias<<<gD, blk, 0, stream>>>(io, kwl, kbl, Qb, M_, D_, D_, 0);
        gemm_bias<<<gD, blk, 0, stream>>>(vin, vwl, vbl, Vb, M_, D_, D_, 0);
        attn_kernel<<<BSZ * H_ * T_, blk, 0, stream>>>(Qb, Qb, Vb, gammas + l * H_, Fb, mtype);
        gemm_bias<<<gD, blk, 0, stream>>>(Fb, owl, obl, Gb, M_, D_, D_, 0);
        add_ln<<<M_, blk, 0, stream>>>(io, Gb, ln1_g + l * D_, ln1_b + l * D_, io, 1e-5f);
        if (ffn) {
            gemm_bias<<<gF, blk, 0, stream>>>(io, ff1_w + (size_t)l * D_ * FF_,
                                              ff1_b + (size_t)l * FF_, Gb, M_, FF_, D_, 1);
            gemm_bias<<<gD, blk, 0, stream>>>(Gb, ff2_w + (size_t)l * FF_ * D_,
                                              ff2_b + (size_t)l * D_, Fb, M_, D_, FF_, 0);
            add_ln<<<M_, blk, 0, stream>>>(io, Fb, ln2_g + l * D_, ln2_b + l * D_, io, 1e-5f);
        }
    };

    layer(0, 1, Y, Y, true);
    layer(1, 1, Y, Y, true);
    layer(2, 1, X, X, false);
    layer(3, 0, X, Y, true);
    layer(4, 1, X, X, false);
    layer(5, 0, X, Y, true);
}

// Round 2
// 7237.587 us; speedup vs baseline: 2.4747x; 2.4747x over previous
//
#include <hip/hip_runtime.h>
#include <math.h>

#define T_  1024
#define D_  512
#define H_  8
#define DK_ 64
#define FF_ 2048
#define BSZ 8
#define M_  (BSZ * T_)   // 8192 rows

// ======================= generic tiled f32 GEMM =======================
#define BM 64
#define BN 64
#define BK 16

__global__ void __launch_bounds__(256) gemm_bias(
    const float* __restrict__ A, const float* __restrict__ B,
    const float* __restrict__ bias, float* __restrict__ C,
    int M, int N, int K, int relu)
{
    __shared__ float As[BK][BM + 4];
    __shared__ float Bs[BK][BN + 4];
    int tid = threadIdx.x;
    int tx = tid & 15, ty = tid >> 4;
    int n0 = blockIdx.x * BN;
    int m0 = blockIdx.y * BM;
    int ar = tid >> 2, ak = (tid & 3) * 4;   // A tile: 64 rows x 16 k
    int br = tid >> 4, bc = (tid & 15) * 4;  // B tile: 16 k x 64 cols

    float acc[4][4] = {};
    for (int k0 = 0; k0 < K; k0 += BK) {
        float4 av = *(const float4*)(A + (size_t)(m0 + ar) * K + (k0 + ak));
        As[ak + 0][ar] = av.x; As[ak + 1][ar] = av.y;
        As[ak + 2][ar] = av.z; As[ak + 3][ar] = av.w;
        float4 bv = *(const float4*)(B + (size_t)(k0 + br) * N + (n0 + bc));
        *(float4*)&Bs[br][bc] = bv;
        __syncthreads();
#pragma unroll
        for (int kk = 0; kk < BK; ++kk) {
            float4 a = *(const float4*)&As[kk][ty * 4];
            float4 b = *(const float4*)&Bs[kk][tx * 4];
            acc[0][0] += a.x * b.x; acc[0][1] += a.x * b.y; acc[0][2] += a.x * b.z; acc[0][3] += a.x * b.w;
            acc[1][0] += a.y * b.x; acc[1][1] += a.y * b.y; acc[1][2] += a.y * b.z; acc[1][3] += a.y * b.w;
            acc[2][0] += a.z * b.x; acc[2][1] += a.z * b.y; acc[2][2] += a.z * b.z; acc[2][3] += a.z * b.w;
            acc[3][0] += a.w * b.x; acc[3][1] += a.w * b.y; acc[3][2] += a.w * b.z; acc[3][3] += a.w * b.w;
        }
        __syncthreads();
    }
    float4 b4 = *(const float4*)(bias + n0 + tx * 4);
#pragma unroll
    for (int r = 0; r < 4; ++r) {
        float4 v;
        v.x = acc[r][0] + b4.x; v.y = acc[r][1] + b4.y;
        v.z = acc[r][2] + b4.z; v.w = acc[r][3] + b4.w;
        if (relu) {
            v.x = fmaxf(v.x, 0.f); v.y = fmaxf(v.y, 0.f);
            v.z = fmaxf(v.z, 0.f); v.w = fmaxf(v.w, 0.f);
        }
        *(float4*)(C + (size_t)(m0 + ty * 4 + r) * N + n0 + tx * 4) = v;
    }
}

// ======================= causal conv1d as 5 shifted GEMMs =======================
__global__ void __launch_bounds__(256) conv_gemm(
    const float* __restrict__ X, const float* __restrict__ W5, float* __restrict__ C)
{
    __shared__ float As[BK][BM + 4];
    __shared__ float Bs[BK][BN + 4];
    int tid = threadIdx.x;
    int tx = tid & 15, ty = tid >> 4;
    int n0 = blockIdx.x * BN;
    int m0 = blockIdx.y * BM;
    int ar = tid >> 2, ak = (tid & 3) * 4;
    int br = tid >> 4, bc = (tid & 15) * 4;

    int m = m0 + ar;
    int t = m & (T_ - 1);
    float acc[4][4] = {};
    for (int ks = 0; ks < 5; ++ks) {
        int shift = ks - 4;
        bool valid = (t + shift) >= 0;
        const float* Bp = W5 + (size_t)ks * D_ * D_;
        const float* Arow = X + (size_t)(valid ? (m + shift) : 0) * D_;
        for (int k0 = 0; k0 < D_; k0 += BK) {
            float4 av = valid ? *(const float4*)(Arow + k0 + ak) : make_float4(0.f, 0.f, 0.f, 0.f);
            As[ak + 0][ar] = av.x; As[ak + 1][ar] = av.y;
            As[ak + 2][ar] = av.z; As[ak + 3][ar] = av.w;
            float4 bv = *(const float4*)(Bp + (size_t)(k0 + br) * D_ + (n0 + bc));
            *(float4*)&Bs[br][bc] = bv;
            __syncthreads();
#pragma unroll
            for (int kk = 0; kk < BK; ++kk) {
                float4 a = *(const float4*)&As[kk][ty * 4];
                float4 b = *(const float4*)&Bs[kk][tx * 4];
                acc[0][0] += a.x * b.x; acc[0][1] += a.x * b.y; acc[0][2] += a.x * b.z; acc[0][3] += a.x * b.w;
                acc[1][0] += a.y * b.x; acc[1][1] += a.y * b.y; acc[1][2] += a.y * b.z; acc[1][3] += a.y * b.w;
                acc[2][0] += a.z * b.x; acc[2][1] += a.z * b.y; acc[2][2] += a.z * b.z; acc[2][3] += a.z * b.w;
                acc[3][0] += a.w * b.x; acc[3][1] += a.w * b.y; acc[3][2] += a.w * b.z; acc[3][3] += a.w * b.w;
            }
            __syncthreads();
        }
    }
#pragma unroll
    for (int r = 0; r < 4; ++r) {
        float4 v;
        v.x = acc[r][0]; v.y = acc[r][1]; v.z = acc[r][2]; v.w = acc[r][3];
        *(float4*)(C + (size_t)(m0 + ty * 4 + r) * D_ + n0 + tx * 4) = v;
    }
}

// repack conv_w (O,I,KS) -> W5[ks][i][o]
__global__ void repack_w(const float* __restrict__ cw, float* __restrict__ W5)
{
    int idx = blockIdx.x * 256 + threadIdx.x;
    if (idx >= 5 * D_ * D_) return;
    int k = idx / (D_ * D_);
    int rem = idx - k * D_ * D_;
    int ii = rem / D_;
    int o = rem - ii * D_;
    W5[idx] = cw[((size_t)o * D_ + ii) * 5 + k];
}

// ======================= smooth pointwise + LayerNorm (eps=1e-12) =======================
__global__ void __launch_bounds__(256) smooth_ln(
    const float* __restrict__ x, const float* __restrict__ trend,
    const float* __restrict__ conv_b, const float* __restrict__ sqrt_beta,
    const float* __restrict__ g, const float* __restrict__ bb,
    float* __restrict__ out)
{
    __shared__ float s_red[8];
    int row = blockIdx.x, tid = threadIdx.x;
    int lane = tid & 63, wid = tid >> 6;
    float2 xv = ((const float2*)(x + (size_t)row * D_))[tid];
    float2 tv = ((const float2*)(trend + (size_t)row * D_))[tid];
    float2 cb = ((const float2*)conv_b)[tid];
    float2 sb = ((const float2*)sqrt_beta)[tid];
    float t0 = tv.x + cb.x, t1 = tv.y + cb.y;
    float v0 = t0 + sb.x * sb.x * (xv.x - t0) + xv.x;
    float v1 = t1 + sb.y * sb.y * (xv.y - t1) + xv.y;
    float s = v0 + v1, sq = v0 * v0 + v1 * v1;
    for (int o = 32; o > 0; o >>= 1) { s += __shfl_xor(s, o, 64); sq += __shfl_xor(sq, o, 64); }
    if (lane == 0) { s_red[wid] = s; s_red[4 + wid] = sq; }
    __syncthreads();
    s = s_red[0] + s_red[1] + s_red[2] + s_red[3];
    sq = s_red[4] + s_red[5] + s_red[6] + s_red[7];
    float mean = s * (1.f / D_);
    float var = sq * (1.f / D_) - mean * mean;
    if (var < 0.f) var = 0.f;
    float rstd = rsqrtf(var + 1e-12f);
    float2 gv = ((const float2*)g)[tid];
    float2 bv = ((const float2*)bb)[tid];
    float2 o2;
    o2.x = gv.x * (v0 - mean) * rstd + bv.x;
    o2.y = gv.y * (v1 - mean) * rstd + bv.y;
    ((float2*)(out + (size_t)row * D_))[tid] = o2;
}

// ======================= residual add + LayerNorm =======================
__global__ void __launch_bounds__(256) add_ln(
    const float* __restrict__ a, const float* __restrict__ c,
    const float* __restrict__ g, const float* __restrict__ bb,
    float* __restrict__ out, float eps)
{
    __shared__ float s_red[8];
    int row = blockIdx.x, tid = threadIdx.x;
    int lane = tid & 63, wid = tid >> 6;
    float2 av = ((const float2*)(a + (size_t)row * D_))[tid];
    float2 cv = ((const float2*)(c + (size_t)row * D_))[tid];
    float v0 = av.x + cv.x;
    float v1 = av.y + cv.y;
    float s = v0 + v1, sq = v0 * v0 + v1 * v1;
    for (int o = 32; o > 0; o >>= 1) { s += __shfl_xor(s, o, 64); sq += __shfl_xor(sq, o, 64); }
    if (lane == 0) { s_red[wid] = s; s_red[4 + wid] = sq; }
    __syncthreads();
    s = s_red[0] + s_red[1] + s_red[2] + s_red[3];
    sq = s_red[4] + s_red[5] + s_red[6] + s_red[7];
    float mean = s * (1.f / D_);
    float var = sq * (1.f / D_) - mean * mean;
    if (var < 0.f) var = 0.f;
    float rstd = rsqrtf(var + eps);
    float2 gv = ((const float2*)g)[tid];
    float2 bv = ((const float2*)bb)[tid];
    float2 o2;
    o2.x = gv.x * (v0 - mean) * rstd + bv.x;
    o2.y = gv.y * (v1 - mean) * rstd + bv.y;
    ((float2*)(out + (size_t)row * D_))[tid] = o2;
}

// ======================= QK^T scores (A·B^T), causal tiles only =======================
// S[z][i][k] = (Q[b,i,h,:]·Q[b,k,h,:]) / 8,  z = bl*8+h, b = bbase+bl.
__global__ void __launch_bounds__(256) qk_kernel(
    const float* __restrict__ Q, float* __restrict__ S, int bbase)
{
    int kt = blockIdx.x, it = blockIdx.y;
    if (kt > it) return;
    int z = blockIdx.z;
    int bl = z >> 3, h = z & 7;
    int b = bbase + bl;
    __shared__ float As[BK][BM + 4];
    __shared__ float Bs[BK][BN + 4];
    int tid = threadIdx.x;
    int tx = tid & 15, ty = tid >> 4;
    int ar = tid >> 2, ak = (tid & 3) * 4;

    const float* Abase = Q + (size_t)(b * T_ + it * 64) * D_ + h * DK_;
    const float* Bbase = Q + (size_t)(b * T_ + kt * 64) * D_ + h * DK_;
    float acc[4][4] = {};
    for (int k0 = 0; k0 < DK_; k0 += BK) {
        float4 av = *(const float4*)(Abase + (size_t)ar * D_ + k0 + ak);
        As[ak + 0][ar] = av.x; As[ak + 1][ar] = av.y;
        As[ak + 2][ar] = av.z; As[ak + 3][ar] = av.w;
        float4 bv = *(const float4*)(Bbase + (size_t)ar * D_ + k0 + ak);
        Bs[ak + 0][ar] = bv.x; Bs[ak + 1][ar] = bv.y;
        Bs[ak + 2][ar] = bv.z; Bs[ak + 3][ar] = bv.w;
        __syncthreads();
#pragma unroll
        for (int kk = 0; kk < BK; ++kk) {
            float4 a = *(const float4*)&As[kk][ty * 4];
            float4 b4 = *(const float4*)&Bs[kk][tx * 4];
            acc[0][0] += a.x * b4.x; acc[0][1] += a.x * b4.y; acc[0][2] += a.x * b4.z; acc[0][3] += a.x * b4.w;
            acc[1][0] += a.y * b4.x; acc[1][1] += a.y * b4.y; acc[1][2] += a.y * b4.z; acc[1][3] += a.y * b4.w;
            acc[2][0] += a.z * b4.x; acc[2][1] += a.z * b4.y; acc[2][2] += a.z * b4.z; acc[2][3] += a.z * b4.w;
            acc[3][0] += a.w * b4.x; acc[3][1] += a.w * b4.y; acc[3][2] += a.w * b4.z; acc[3][3] += a.w * b4.w;
        }
        __syncthreads();
    }
    float* out = S + ((size_t)z * T_ + it * 64) * T_ + kt * 64;
#pragma unroll
    for (int r = 0; r < 4; ++r) {
        float4 v;
        v.x = acc[r][0] * 0.125f; v.y = acc[r][1] * 0.125f;
        v.z = acc[r][2] * 0.125f; v.w = acc[r][3] * 0.125f;
        *(float4*)(out + (size_t)(ty * 4 + r) * T_ + tx * 4) = v;
    }
}

// ======================= per-row decay + double softmax (in place S -> P) =======================
__global__ void __launch_bounds__(256) decay_rows(
    float* __restrict__ S, const float* __restrict__ gam_l, int mtype)
{
    __shared__ float s_red[8];
    int i = blockIdx.x;
    int z = blockIdx.y;
    int h = z & 7;
    float* row = S + ((size_t)z * T_ + i) * T_;
    int tid = threadIdx.x, lane = tid & 63, wid = tid >> 6;
    int kmax = (mtype == 0) ? (i - 1) : i;
    int wmax = i | 63;          // last col the PV tile will read
    int k0 = tid * 4;

    if (kmax < 0) {             // mtype==0, i==0: zero_pad row
        if (k0 <= wmax) *(float4*)(row + k0) = make_float4(0.f, 0.f, 0.f, 0.f);
        return;
    }

    float sc[4];
    if (k0 + 3 <= kmax) {
        float4 v = *(const float4*)(row + k0);
        sc[0] = v.x; sc[1] = v.y; sc[2] = v.z; sc[3] = v.w;
    } else {
#pragma unroll
        for (int j = 0; j < 4; ++j)
            sc[j] = (k0 + j <= kmax) ? row[k0 + j] : -1e30f;
    }

    // ---- softmax #1 ----
    float mx = fmaxf(fmaxf(sc[0], sc[1]), fmaxf(sc[2], sc[3]));
    for (int o = 32; o > 0; o >>= 1) mx = fmaxf(mx, __shfl_xor(mx, o, 64));
    if (lane == 0) s_red[wid] = mx;
    __syncthreads();
    mx = fmaxf(fmaxf(s_red[0], s_red[1]), fmaxf(s_red[2], s_red[3]));
    __syncthreads();

    float p[4]; float ls = 0.f;
#pragma unroll
    for (int j = 0; j < 4; ++j) {
        p[j] = (k0 + j <= kmax) ? __expf(sc[j] - mx) : 0.f;
        ls += p[j];
    }
    float ssum = ls;
    for (int o = 32; o > 0; o >>= 1) ssum += __shfl_xor(ssum, o, 64);
    if (lane == 0) s_red[wid] = ssum;
    __syncthreads();
    float denom = s_red[0] + s_red[1] + s_red[2] + s_red[3];
    __syncthreads();
    float inv1 = 1.f / denom;
#pragma unroll
    for (int j = 0; j < 4; ++j) p[j] *= inv1;

    // ---- inclusive cumsum over k ----
    float tsum = p[0] + p[1] + p[2] + p[3];
    float incl = tsum;
    for (int o = 1; o < 64; o <<= 1) {
        float y = __shfl_up(incl, o, 64);
        if (lane >= o) incl += y;
    }
    if (lane == 63) s_red[wid] = incl;
    __syncthreads();
    float woff = 0.f;
    for (int w = 0; w < wid; ++w) woff += s_red[w];
    float total = s_red[0] + s_red[1] + s_red[2] + s_red[3];
    __syncthreads();
    float run = woff + incl - tsum;

    // ---- distance effect on raw scores ----
    float gp = gam_l[h];
    float gam = -log1pf(__expf(gp));
#pragma unroll
    for (int j = 0; j < 4; ++j) {
        int k = k0 + j;
        run += p[j];
        float rem = total - run;
        if (rem < 0.f) rem = 0.f;
        float pos = fabsf((float)(k - i));
        float dist = sqrtf(rem * pos);
        float eff = __expf(dist * gam);
        eff = fminf(fmaxf(eff, 1e-5f), 1e5f);
        sc[j] = (k <= kmax) ? sc[j] * eff : -1e30f;
    }

    // ---- softmax #2 ----
    mx = fmaxf(fmaxf(sc[0], sc[1]), fmaxf(sc[2], sc[3]));
    for (int o = 32; o > 0; o >>= 1) mx = fmaxf(mx, __shfl_xor(mx, o, 64));
    if (lane == 0) s_red[wid] = mx;
    __syncthreads();
    mx = fmaxf(fmaxf(s_red[0], s_red[1]), fmaxf(s_red[2], s_red[3]));
    __syncthreads();
    ls = 0.f;
#pragma unroll
    for (int j = 0; j < 4; ++j) {
        p[j] = (k0 + j <= kmax) ? __expf(sc[j] - mx) : 0.f;
        ls += p[j];
    }
    ssum = ls;
    for (int o = 32; o > 0; o >>= 1) ssum += __shfl_xor(ssum, o, 64);
    if (lane == 0) s_red[wid] = ssum;
    __syncthreads();
    float denom2 = s_red[0] + s_red[1] + s_red[2] + s_red[3];
    float inv2 = 1.f / denom2;

    if (k0 <= wmax) {
        float4 v;
        v.x = p[0] * inv2; v.y = p[1] * inv2;
        v.z = p[2] * inv2; v.w = p[3] * inv2;
        *(float4*)(row + k0) = v;
    }
}

// ======================= PV GEMM (causal K-bound), writes concat layout =======================
__global__ void __launch_bounds__(256) pv_kernel(
    const float* __restrict__ P, const float* __restrict__ V,
    float* __restrict__ O, int bbase)
{
    int mt = blockIdx.x;
    int z = blockIdx.y;
    int bl = z >> 3, h = z & 7;
    int b = bbase + bl;
    __shared__ float As[BK][BM + 4];
    __shared__ float Bs[BK][BN + 4];
    int tid = threadIdx.x;
    int tx = tid & 15, ty = tid >> 4;
    int ar = tid >> 2, ak = (tid & 3) * 4;
    int br = tid >> 4, bc = (tid & 15) * 4;

    const float* Ab = P + ((size_t)z * T_ + mt * 64) * T_;
    const float* Bb = V + (size_t)(b * T_) * D_ + h * DK_;
    int kend = mt * 64 + 64;

    float acc[4][4] = {};
    for (int k0 = 0; k0 < kend; k0 += BK) {
        float4 av = *(const float4*)(Ab + (size_t)ar * T_ + k0 + ak);
        As[ak + 0][ar] = av.x; As[ak + 1][ar] = av.y;
        As[ak + 2][ar] = av.z; As[ak + 3][ar] = av.w;
        float4 bv = *(const float4*)(Bb + (size_t)(k0 + br) * D_ + bc);
        *(float4*)&Bs[br][bc] = bv;
        __syncthreads();
#pragma unroll
        for (int kk = 0; kk < BK; ++kk) {
            float4 a = *(const float4*)&As[kk][ty * 4];
            float4 b4 = *(const float4*)&Bs[kk][tx * 4];
            acc[0][0] += a.x * b4.x; acc[0][1] += a.x * b4.y; acc[0][2] += a.x * b4.z; acc[0][3] += a.x * b4.w;
            acc[1][0] += a.y * b4.x; acc[1][1] += a.y * b4.y; acc[1][2] += a.y * b4.z; acc[1][3] += a.y * b4.w;
            acc[2][0] += a.z * b4.x; acc[2][1] += a.z * b4.y; acc[2][2] += a.z * b4.z; acc[2][3] += a.z * b4.w;
            acc[3][0] += a.w * b4.x; acc[3][1] += a.w * b4.y; acc[3][2] += a.w * b4.z; acc[3][3] += a.w * b4.w;
        }
        __syncthreads();
    }
    float* out = O + (size_t)(b * T_ + mt * 64) * D_ + h * DK_;
#pragma unroll
    for (int r = 0; r < 4; ++r) {
        float4 v;
        v.x = acc[r][0]; v.y = acc[r][1]; v.z = acc[r][2]; v.w = acc[r][3];
        *(float4*)(out + (size_t)(ty * 4 + r) * D_ + tx * 4) = v;
    }
}

// ======================= launch =======================
extern "C" void kernel_launch(void* const* d_in, const int* in_sizes, int n_in,
                              void* d_out, int out_size, void* d_ws, size_t ws_size,
                              hipStream_t stream)
{
    const float* q_embed   = (const float*)d_in[0];
    const float* qa_embed  = (const float*)d_in[1];
    const float* conv_w    = (const float*)d_in[3];
    const float* conv_b    = (const float*)d_in[4];
    const float* sqrt_beta = (const float*)d_in[5];
    const float* sm_g      = (const float*)d_in[6];
    const float* sm_b      = (const float*)d_in[7];
    const float* k_w       = (const float*)d_in[8];
    const float* k_b       = (const float*)d_in[9];
    const float* v_w       = (const float*)d_in[10];
    const float* v_b       = (const float*)d_in[11];
    const float* out_w     = (const float*)d_in[12];
    const float* out_b     = (const float*)d_in[13];
    const float* gammas    = (const float*)d_in[14];
    const float* ln1_g     = (const float*)d_in[15];
    const float* ln1_b     = (const float*)d_in[16];
    const float* ff1_w     = (const float*)d_in[17];
    const float* ff1_b     = (const float*)d_in[18];
    const float* ff2_w     = (const float*)d_in[19];
    const float* ff2_b     = (const float*)d_in[20];
    const float* ln2_g     = (const float*)d_in[21];
    const float* ln2_b     = (const float*)d_in[22];

    const size_t NT = (size_t)M_ * D_;   // 4,194,304 floats
    float* X  = (float*)d_out;           // x-stream lives in d_out
    float* ws = (float*)d_ws;
    float* Y  = ws;                      // y-stream
    float* Qb = ws + NT;                 // q (== k) projection
    float* Vb = ws + 2 * NT;             // v projection
    float* Fb = ws + 3 * NT;             // trend / attn-concat / ffn-out
    float* Gb = ws + 4 * NT;             // scores chunk (2b) / q2 / ffn-hidden (64 MB)
    float* W5 = ws + 4 * NT + (size_t)M_ * FF_;  // repacked conv weights

    dim3 blk(256);
    dim3 gD(D_ / BN, M_ / BM);
    dim3 gF(FF_ / BN, M_ / BM);

    repack_w<<<(5 * D_ * D_ + 255) / 256, blk, 0, stream>>>(conv_w, W5);

    conv_gemm<<<gD, blk, 0, stream>>>(q_embed, W5, Fb);
    smooth_ln<<<M_, blk, 0, stream>>>(q_embed, Fb, conv_b, sqrt_beta, sm_g, sm_b, X);
    conv_gemm<<<gD, blk, 0, stream>>>(qa_embed, W5, Fb);
    smooth_ln<<<M_, blk, 0, stream>>>(qa_embed, Fb, conv_b, sqrt_beta, sm_g, sm_b, Y);

    auto layer = [&](int l, int mtype, float* io, const float* vin, bool ffn) {
        const float* kwl = k_w + (size_t)l * D_ * D_;
        const float* kbl = k_b + (size_t)l * D_;
        const float* vwl = v_w + (size_t)l * D_ * D_;
        const float* vbl = v_b + (size_t)l * D_;
        const float* owl = out_w + (size_t)l * D_ * D_;
        const float* obl = out_b + (size_t)l * D_;
        gemm_bias<<<gD, blk, 0, stream>>>(io, kwl, kbl, Qb, M_, D_, D_, 0);
        gemm_bias<<<gD, blk, 0, stream>>>(vin, vwl, vbl, Vb, M_, D_, D_, 0);
        for (int c = 0; c < 4; ++c) {   // 2 batches per chunk; S lives in Gb (64 MB)
            qk_kernel<<<dim3(16, 16, 16), blk, 0, stream>>>(Qb, Gb, c * 2);
            decay_rows<<<dim3(T_, 16), blk, 0, stream>>>(Gb, gammas + l * H_, mtype);
            pv_kernel<<<dim3(16, 16), blk, 0, stream>>>(Gb, Vb, Fb, c * 2);
        }
        gemm_bias<<<gD, blk, 0, stream>>>(Fb, owl, obl, Gb, M_, D_, D_, 0);
        add_ln<<<M_, blk, 0, stream>>>(io, Gb, ln1_g + l * D_, ln1_b + l * D_, io, 1e-5f);
        if (ffn) {
            gemm_bias<<<gF, blk, 0, stream>>>(io, ff1_w + (size_t)l * D_ * FF_,
                                              ff1_b + (size_t)l * FF_, Gb, M_, FF_, D_, 1);
            gemm_bias<<<gD, blk, 0, stream>>>(Gb, ff2_w + (size_t)l * FF_ * D_,
                                              ff2_b + (size_t)l * D_, Fb, M_, D_, FF_, 0);
            add_ln<<<M_, blk, 0, stream>>>(io, Fb, ln2_g + l * D_, ln2_b + l * D_, io, 1e-5f);
        }
    };

    layer(0, 1, Y, Y, true);
    layer(1, 1, Y, Y, true);
    layer(2, 1, X, X, false);
    layer(3, 0, X, Y, true);
    layer(4, 1, X, X, false);
    layer(5, 0, X, Y, true);
}

// Round 3
// 6304.407 us; speedup vs baseline: 2.8410x; 1.1480x over previous
//
#include <hip/hip_runtime.h>
#include <math.h>

#define T_  1024
#define D_  512
#define H_  8
#define DK_ 64
#define FF_ 2048
#define BSZ 8
#define M_  (BSZ * T_)   // 8192 rows
#define TP_ (T_ + 4)     // padded rows per batch for causal conv

typedef unsigned short u16;
typedef __attribute__((ext_vector_type(8))) __bf16 bf16x8;
typedef __attribute__((ext_vector_type(4))) float f32x4;

__device__ __forceinline__ u16 f2bf(float f) {            // RNE f32 -> bf16 bits
    unsigned int u = __float_as_uint(f);
    u += 0x7fffu + ((u >> 16) & 1u);
    return (u16)(u >> 16);
}

__device__ __forceinline__ void gload16(const void* g, void* l) {
    // async global->LDS, 16B/lane; LDS dest = wave-uniform base + lane*16
    __builtin_amdgcn_global_load_lds(
        (const __attribute__((address_space(1))) void*)g,
        (__attribute__((address_space(3))) void*)l, 16, 0, 0);
}

// ======================= bf16 MFMA GEMM (m97 structure) =======================
// C[M][N] = A[M][K](bf16) * Bt[N][K]^T(bf16) + bias. 128x128 tile, 4 waves,
// each wave 4x4 of 16x16x32 MFMA. mode 0: f32 out; 1: bf16 out + relu.
__global__ void __launch_bounds__(256) gemm_mfma(
    const u16* __restrict__ A, const u16* __restrict__ Bt,
    const float* __restrict__ bias, void* __restrict__ Cout,
    int N, int K, int mode)
{
    __shared__ __align__(16) u16 As[128 * 32];
    __shared__ __align__(16) u16 Bs[128 * 32];
    int tid = threadIdx.x;
    int wid = tid >> 6, lane = tid & 63;
    int quad = lane >> 4, mrow = lane & 15;
    int m0 = blockIdx.y * 128, n0 = blockIdx.x * 128;
    int wr = (wid >> 1) * 64, wc = (wid & 1) * 64;

    const u16* Ap = A + (size_t)(m0 + (tid >> 2)) * K + (tid & 3) * 8;
    const u16* Bp = Bt + (size_t)(n0 + (tid >> 2)) * K + (tid & 3) * 8;
    char* lA = (char*)As + wid * 1024;
    char* lB = (char*)Bs + wid * 1024;

    f32x4 acc[4][4] = {};
    for (int k0 = 0; k0 < K; k0 += 32) {
        __syncthreads();
        gload16(Ap + k0, lA);
        gload16(Ap + (size_t)64 * K + k0, lA + 4096);
        gload16(Bp + k0, lB);
        gload16(Bp + (size_t)64 * K + k0, lB + 4096);
        asm volatile("s_waitcnt vmcnt(0)" ::: "memory");
        __syncthreads();
        bf16x8 af[4], bf[4];
#pragma unroll
        for (int t = 0; t < 4; ++t) {
            af[t] = *(const bf16x8*)&As[(wr + t * 16 + mrow) * 32 + quad * 8];
            bf[t] = *(const bf16x8*)&Bs[(wc + t * 16 + mrow) * 32 + quad * 8];
        }
#pragma unroll
        for (int rt = 0; rt < 4; ++rt)
#pragma unroll
            for (int ct = 0; ct < 4; ++ct)
                acc[rt][ct] = __builtin_amdgcn_mfma_f32_16x16x32_bf16(
                    af[rt], bf[ct], acc[rt][ct], 0, 0, 0);
    }

#pragma unroll
    for (int ct = 0; ct < 4; ++ct) {
        int col = n0 + wc + ct * 16 + mrow;
        float bv = bias ? bias[col] : 0.f;
#pragma unroll
        for (int rt = 0; rt < 4; ++rt) {
            int row = m0 + wr + rt * 16 + quad * 4;
            if (mode == 0) {
                float* C = (float*)Cout;
#pragma unroll
                for (int e = 0; e < 4; ++e)
                    C[(size_t)(row + e) * N + col] = acc[rt][ct][e] + bv;
            } else {
                u16* C = (u16*)Cout;
#pragma unroll
                for (int e = 0; e < 4; ++e)
                    C[(size_t)(row + e) * N + col] = f2bf(fmaxf(acc[rt][ct][e] + bv, 0.f));
            }
        }
    }
}

// ======================= causal conv1d: 5 shifted MFMA passes =======================
// Xp: bf16 [BSZ][TP_][D_] (4 zero pad rows per batch). W5t: bf16 [ks][o][i].
// trend f32 out (conv_b added later in smooth_ln).
__global__ void __launch_bounds__(256) conv_mfma(
    const u16* __restrict__ Xp, const u16* __restrict__ W5t, float* __restrict__ C)
{
    __shared__ __align__(16) u16 As[128 * 32];
    __shared__ __align__(16) u16 Bs[128 * 32];
    int tid = threadIdx.x;
    int wid = tid >> 6, lane = tid & 63;
    int quad = lane >> 4, mrow = lane & 15;
    int m0 = blockIdx.y * 128, n0 = blockIdx.x * 128;
    int wr = (wid >> 1) * 64, wc = (wid & 1) * 64;
    int b = m0 >> 10, tloc = m0 & (T_ - 1);

    const u16* Ap0 = Xp + (size_t)(b * TP_ + tloc + (tid >> 2)) * D_ + (tid & 3) * 8;
    const u16* Bp0 = W5t + (size_t)(n0 + (tid >> 2)) * D_ + (tid & 3) * 8;
    char* lA = (char*)As + wid * 1024;
    char* lB = (char*)Bs + wid * 1024;

    f32x4 acc[4][4] = {};
    for (int ks = 0; ks < 5; ++ks) {
        const u16* Ap = Ap0 + ks * D_;              // shift = +1 padded row per ks
        const u16* Bp = Bp0 + (size_t)ks * D_ * D_;
        for (int k0 = 0; k0 < D_; k0 += 32) {
            __syncthreads();
            gload16(Ap + k0, lA);
            gload16(Ap + (size_t)64 * D_ + k0, lA + 4096);
            gload16(Bp + k0, lB);
            gload16(Bp + (size_t)64 * D_ + k0, lB + 4096);
            asm volatile("s_waitcnt vmcnt(0)" ::: "memory");
            __syncthreads();
            bf16x8 af[4], bf[4];
#pragma unroll
            for (int t = 0; t < 4; ++t) {
                af[t] = *(const bf16x8*)&As[(wr + t * 16 + mrow) * 32 + quad * 8];
                bf[t] = *(const bf16x8*)&Bs[(wc + t * 16 + mrow) * 32 + quad * 8];
            }
#pragma unroll
            for (int rt = 0; rt < 4; ++rt)
#pragma unroll
                for (int ct = 0; ct < 4; ++ct)
                    acc[rt][ct] = __builtin_amdgcn_mfma_f32_16x16x32_bf16(
                        af[rt], bf[ct], acc[rt][ct], 0, 0, 0);
        }
    }
#pragma unroll
    for (int ct = 0; ct < 4; ++ct) {
        int col = n0 + wc + ct * 16 + mrow;
#pragma unroll
        for (int rt = 0; rt < 4; ++rt) {
            int row = m0 + wr + rt * 16 + quad * 4;
#pragma unroll
            for (int e = 0; e < 4; ++e)
                C[(size_t)(row + e) * D_ + col] = acc[rt][ct][e];
        }
    }
}

// ======================= prep kernels =======================
// f32 [K][N] (L matrices) -> bf16 [N][K]
__global__ void __launch_bounds__(256) transpose_bf16(
    const float* __restrict__ W, u16* __restrict__ Wt, int K, int N)
{
    __shared__ float tile[32][33];
    size_t base = (size_t)blockIdx.z * K * N;
    W += base; Wt += base;
    int k0 = blockIdx.y * 32, n0 = blockIdx.x * 32;
    int r = threadIdx.x >> 3, c = (threadIdx.x & 7) * 4;
    float4 v = *(const float4*)(W + (size_t)(k0 + r) * N + n0 + c);
    tile[r][c] = v.x; tile[r][c + 1] = v.y; tile[r][c + 2] = v.z; tile[r][c + 3] = v.w;
    __syncthreads();
    ushort4 o;
    o.x = f2bf(tile[c + 0][r]); o.y = f2bf(tile[c + 1][r]);
    o.z = f2bf(tile[c + 2][r]); o.w = f2bf(tile[c + 3][r]);
    *(ushort4*)(Wt + (size_t)(n0 + r) * K + k0 + c) = o;
}

// conv_w (O,I,KS) -> W5t[ks][o][i] bf16
__global__ void w5_gather(const float* __restrict__ cw, u16* __restrict__ W5t)
{
    int idx = blockIdx.x * 256 + threadIdx.x;
    if (idx >= 5 * D_ * D_) return;
    int ks = idx / (D_ * D_);
    int rem = idx - ks * (D_ * D_);
    int o = rem >> 9, i = rem & (D_ - 1);
    W5t[idx] = f2bf(cw[((size_t)o * D_ + i) * 5 + ks]);
}

// embeddings f32 [B][T][D] -> bf16 padded [B][TP_][D] (4 leading zero rows/batch)
__global__ void cast_pad(const float* __restrict__ x, const float* __restrict__ y,
                         u16* __restrict__ Xp, u16* __restrict__ Yp)
{
    int idx = blockIdx.x * 256 + threadIdx.x;
    if (idx >= BSZ * TP_ * D_) return;
    int d = idx & (D_ - 1);
    int rowp = idx >> 9;
    int b = rowp / TP_;
    int t = rowp - b * TP_;
    u16 vx = 0, vy = 0;
    if (t >= 4) {
        size_t src = ((size_t)(b * T_ + t - 4) << 9) + d;
        vx = f2bf(x[src]); vy = f2bf(y[src]);
    }
    Xp[idx] = vx; Yp[idx] = vy;
}

// ======================= smooth pointwise + LayerNorm (eps=1e-12) =======================
__global__ void __launch_bounds__(256) smooth_ln(
    const float* __restrict__ x, const float* __restrict__ trend,
    const float* __restrict__ conv_b, const float* __restrict__ sqrt_beta,
    const float* __restrict__ g, const float* __restrict__ bb,
    float* __restrict__ out, u16* __restrict__ outb)
{
    __shared__ float s_red[8];
    int row = blockIdx.x, tid = threadIdx.x;
    int lane = tid & 63, wid = tid >> 6;
    float2 xv = ((const float2*)(x + (size_t)row * D_))[tid];
    float2 tv = ((const float2*)(trend + (size_t)row * D_))[tid];
    float2 cb = ((const float2*)conv_b)[tid];
    float2 sb = ((const float2*)sqrt_beta)[tid];
    float t0 = tv.x + cb.x, t1 = tv.y + cb.y;
    float v0 = t0 + sb.x * sb.x * (xv.x - t0) + xv.x;
    float v1 = t1 + sb.y * sb.y * (xv.y - t1) + xv.y;
    float s = v0 + v1, sq = v0 * v0 + v1 * v1;
    for (int o = 32; o > 0; o >>= 1) { s += __shfl_xor(s, o, 64); sq += __shfl_xor(sq, o, 64); }
    if (lane == 0) { s_red[wid] = s; s_red[4 + wid] = sq; }
    __syncthreads();
    s = s_red[0] + s_red[1] + s_red[2] + s_red[3];
    sq = s_red[4] + s_red[5] + s_red[6] + s_red[7];
    float mean = s * (1.f / D_);
    float var = sq * (1.f / D_) - mean * mean;
    if (var < 0.f) var = 0.f;
    float rstd = rsqrtf(var + 1e-12f);
    float2 gv = ((const float2*)g)[tid];
    float2 bv = ((const float2*)bb)[tid];
    float2 o2;
    o2.x = gv.x * (v0 - mean) * rstd + bv.x;
    o2.y = gv.y * (v1 - mean) * rstd + bv.y;
    ((float2*)(out + (size_t)row * D_))[tid] = o2;
    ushort2 ob; ob.x = f2bf(o2.x); ob.y = f2bf(o2.y);
    ((ushort2*)(outb + (size_t)row * D_))[tid] = ob;
}

// ======================= residual add + LayerNorm (f32 + bf16 out) =======================
__global__ void __launch_bounds__(256) add_ln(
    const float* __restrict__ a, const float* __restrict__ c,
    const float* __restrict__ g, const float* __restrict__ bb,
    float* __restrict__ out, u16* __restrict__ outb, float eps)
{
    __shared__ float s_red[8];
    int row = blockIdx.x, tid = threadIdx.x;
    int lane = tid & 63, wid = tid >> 6;
    float2 av = ((const float2*)(a + (size_t)row * D_))[tid];
    float2 cv = ((const float2*)(c + (size_t)row * D_))[tid];
    float v0 = av.x + cv.x;
    float v1 = av.y + cv.y;
    float s = v0 + v1, sq = v0 * v0 + v1 * v1;
    for (int o = 32; o > 0; o >>= 1) { s += __shfl_xor(s, o, 64); sq += __shfl_xor(sq, o, 64); }
    if (lane == 0) { s_red[wid] = s; s_red[4 + wid] = sq; }
    __syncthreads();
    s = s_red[0] + s_red[1] + s_red[2] + s_red[3];
    sq = s_red[4] + s_red[5] + s_red[6] + s_red[7];
    float mean = s * (1.f / D_);
    float var = sq * (1.f / D_) - mean * mean;
    if (var < 0.f) var = 0.f;
    float rstd = rsqrtf(var + eps);
    float2 gv = ((const float2*)g)[tid];
    float2 bv = ((const float2*)bb)[tid];
    float2 o2;
    o2.x = gv.x * (v0 - mean) * rstd + bv.x;
    o2.y = gv.y * (v1 - mean) * rstd + bv.y;
    ((float2*)(out + (size_t)row * D_))[tid] = o2;
    ushort2 ob; ob.x = f2bf(o2.x); ob.y = f2bf(o2.y);
    ((ushort2*)(outb + (size_t)row * D_))[tid] = ob;
}

// ======================= QK^T scores (f32), causal tiles, one batch =======================
#define BM 64
#define BN 64
#define BK 16
__global__ void __launch_bounds__(256) qk_kernel(
    const float* __restrict__ Q, float* __restrict__ S, int b)
{
    int kt = blockIdx.x, it = blockIdx.y;
    if (kt > it) return;
    int h = blockIdx.z;
    __shared__ float As[BK][BM + 4];
    __shared__ float Bs[BK][BN + 4];
    int tid = threadIdx.x;
    int tx = tid & 15, ty = tid >> 4;
    int ar = tid >> 2, ak = (tid & 3) * 4;

    const float* Abase = Q + (size_t)(b * T_ + it * 64) * D_ + h * DK_;
    const float* Bbase = Q + (size_t)(b * T_ + kt * 64) * D_ + h * DK_;
    float acc[4][4] = {};
    for (int k0 = 0; k0 < DK_; k0 += BK) {
        float4 av = *(const float4*)(Abase + (size_t)ar * D_ + k0 + ak);
        As[ak + 0][ar] = av.x; As[ak + 1][ar] = av.y;
        As[ak + 2][ar] = av.z; As[ak + 3][ar] = av.w;
        float4 bv = *(const float4*)(Bbase + (size_t)ar * D_ + k0 + ak);
        Bs[ak + 0][ar] = bv.x; Bs[ak + 1][ar] = bv.y;
        Bs[ak + 2][ar] = bv.z; Bs[ak + 3][ar] = bv.w;
        __syncthreads();
#pragma unroll
        for (int kk = 0; kk < BK; ++kk) {
            float4 a = *(const float4*)&As[kk][ty * 4];
            float4 b4 = *(const float4*)&Bs[kk][tx * 4];
            acc[0][0] += a.x * b4.x; acc[0][1] += a.x * b4.y; acc[0][2] += a.x * b4.z; acc[0][3] += a.x * b4.w;
            acc[1][0] += a.y * b4.x; acc[1][1] += a.y * b4.y; acc[1][2] += a.y * b4.z; acc[1][3] += a.y * b4.w;
            acc[2][0] += a.z * b4.x; acc[2][1] += a.z * b4.y; acc[2][2] += a.z * b4.z; acc[2][3] += a.z * b4.w;
            acc[3][0] += a.w * b4.x; acc[3][1] += a.w * b4.y; acc[3][2] += a.w * b4.z; acc[3][3] += a.w * b4.w;
        }
        __syncthreads();
    }
    float* out = S + ((size_t)h * T_ + it * 64) * T_ + kt * 64;
#pragma unroll
    for (int r = 0; r < 4; ++r) {
        float4 v;
        v.x = acc[r][0] * 0.125f; v.y = acc[r][1] * 0.125f;
        v.z = acc[r][2] * 0.125f; v.w = acc[r][3] * 0.125f;
        *(float4*)(out + (size_t)(ty * 4 + r) * T_ + tx * 4) = v;
    }
}

// ======================= per-row decay + double softmax (in place, one batch) =======================
__global__ void __launch_bounds__(256) decay_rows(
    float* __restrict__ S, const float* __restrict__ gam_l, int mtype)
{
    __shared__ float s_red[8];
    int i = blockIdx.x;
    int h = blockIdx.y;
    float* row = S + ((size_t)h * T_ + i) * T_;
    int tid = threadIdx.x, lane = tid & 63, wid = tid >> 6;
    int kmax = (mtype == 0) ? (i - 1) : i;
    int wmax = i | 63;
    int k0 = tid * 4;

    if (kmax < 0) {
        if (k0 <= wmax) *(float4*)(row + k0) = make_float4(0.f, 0.f, 0.f, 0.f);
        return;
    }

    float sc[4];
    if (k0 + 3 <= kmax) {
        float4 v = *(const float4*)(row + k0);
        sc[0] = v.x; sc[1] = v.y; sc[2] = v.z; sc[3] = v.w;
    } else {
#pragma unroll
        for (int j = 0; j < 4; ++j)
            sc[j] = (k0 + j <= kmax) ? row[k0 + j] : -1e30f;
    }

    float mx = fmaxf(fmaxf(sc[0], sc[1]), fmaxf(sc[2], sc[3]));
    for (int o = 32; o > 0; o >>= 1) mx = fmaxf(mx, __shfl_xor(mx, o, 64));
    if (lane == 0) s_red[wid] = mx;
    __syncthreads();
    mx = fmaxf(fmaxf(s_red[0], s_red[1]), fmaxf(s_red[2], s_red[3]));
    __syncthreads();

    float p[4]; float ls = 0.f;
#pragma unroll
    for (int j = 0; j < 4; ++j) {
        p[j] = (k0 + j <= kmax) ? __expf(sc[j] - mx) : 0.f;
        ls += p[j];
    }
    float ssum = ls;
    for (int o = 32; o > 0; o >>= 1) ssum += __shfl_xor(ssum, o, 64);
    if (lane == 0) s_red[wid] = ssum;
    __syncthreads();
    float denom = s_red[0] + s_red[1] + s_red[2] + s_red[3];
    __syncthreads();
    float inv1 = 1.f / denom;
#pragma unroll
    for (int j = 0; j < 4; ++j) p[j] *= inv1;

    float tsum = p[0] + p[1] + p[2] + p[3];
    float incl = tsum;
    for (int o = 1; o < 64; o <<= 1) {
        float y = __shfl_up(incl, o, 64);
        if (lane >= o) incl += y;
    }
    if (lane == 63) s_red[wid] = incl;
    __syncthreads();
    float woff = 0.f;
    for (int w = 0; w < wid; ++w) woff += s_red[w];
    float total = s_red[0] + s_red[1] + s_red[2] + s_red[3];
    __syncthreads();
    float run = woff + incl - tsum;

    float gp = gam_l[h];
    float gam = -log1pf(__expf(gp));
#pragma unroll
    for (int j = 0; j < 4; ++j) {
        int k = k0 + j;
        run += p[j];
        float rem = total - run;
        if (rem < 0.f) rem = 0.f;
        float pos = fabsf((float)(k - i));
        float dist = sqrtf(rem * pos);
        float eff = __expf(dist * gam);
        eff = fminf(fmaxf(eff, 1e-5f), 1e5f);
        sc[j] = (k <= kmax) ? sc[j] * eff : -1e30f;
    }

    mx = fmaxf(fmaxf(sc[0], sc[1]), fmaxf(sc[2], sc[3]));
    for (int o = 32; o > 0; o >>= 1) mx = fmaxf(mx, __shfl_xor(mx, o, 64));
    if (lane == 0) s_red[wid] = mx;
    __syncthreads();
    mx = fmaxf(fmaxf(s_red[0], s_red[1]), fmaxf(s_red[2], s_red[3]));
    __syncthreads();
    ls = 0.f;
#pragma unroll
    for (int j = 0; j < 4; ++j) {
        p[j] = (k0 + j <= kmax) ? __expf(sc[j] - mx) : 0.f;
        ls += p[j];
    }
    ssum = ls;
    for (int o = 32; o > 0; o >>= 1) ssum += __shfl_xor(ssum, o, 64);
    if (lane == 0) s_red[wid] = ssum;
    __syncthreads();
    float denom2 = s_red[0] + s_red[1] + s_red[2] + s_red[3];
    float inv2 = 1.f / denom2;

    if (k0 <= wmax) {
        float4 v;
        v.x = p[0] * inv2; v.y = p[1] * inv2;
        v.z = p[2] * inv2; v.w = p[3] * inv2;
        *(float4*)(row + k0) = v;
    }
}

// ======================= PV GEMM (causal K-bound), bf16 concat out =======================
__global__ void __launch_bounds__(256) pv_kernel(
    const float* __restrict__ P, const float* __restrict__ V,
    u16* __restrict__ O, int b)
{
    int mt = blockIdx.x;
    int h = blockIdx.y;
    __shared__ float As[BK][BM + 4];
    __shared__ float Bs[BK][BN + 4];
    int tid = threadIdx.x;
    int tx = tid & 15, ty = tid >> 4;
    int ar = tid >> 2, ak = (tid & 3) * 4;
    int br = tid >> 4, bc = (tid & 15) * 4;

    const float* Ab = P + ((size_t)h * T_ + mt * 64) * T_;
    const float* Bb = V + (size_t)(b * T_) * D_ + h * DK_;
    int kend = mt * 64 + 64;

    float acc[4][4] = {};
    for (int k0 = 0; k0 < kend; k0 += BK) {
        float4 av = *(const float4*)(Ab + (size_t)ar * T_ + k0 + ak);
        As[ak + 0][ar] = av.x; As[ak + 1][ar] = av.y;
        As[ak + 2][ar] = av.z; As[ak + 3][ar] = av.w;
        float4 bv = *(const float4*)(Bb + (size_t)(k0 + br) * D_ + bc);
        *(float4*)&Bs[br][bc] = bv;
        __syncthreads();
#pragma unroll
        for (int kk = 0; kk < BK; ++kk) {
            float4 a = *(const float4*)&As[kk][ty * 4];
            float4 b4 = *(const float4*)&Bs[kk][tx * 4];
            acc[0][0] += a.x * b4.x; acc[0][1] += a.x * b4.y; acc[0][2] += a.x * b4.z; acc[0][3] += a.x * b4.w;
            acc[1][0] += a.y * b4.x; acc[1][1] += a.y * b4.y; acc[1][2] += a.y * b4.z; acc[1][3] += a.y * b4.w;
            acc[2][0] += a.z * b4.x; acc[2][1] += a.z * b4.y; acc[2][2] += a.z * b4.z; acc[2][3] += a.z * b4.w;
            acc[3][0] += a.w * b4.x; acc[3][1] += a.w * b4.y; acc[3][2] += a.w * b4.z; acc[3][3] += a.w * b4.w;
        }
        __syncthreads();
    }
    u16* out = O + (size_t)(b * T_ + mt * 64) * D_ + h * DK_;
#pragma unroll
    for (int r = 0; r < 4; ++r) {
        ushort4 v;
        v.x = f2bf(acc[r][0]); v.y = f2bf(acc[r][1]);
        v.z = f2bf(acc[r][2]); v.w = f2bf(acc[r][3]);
        *(ushort4*)(out + (size_t)(ty * 4 + r) * D_ + tx * 4) = v;
    }
}

// ======================= launch =======================
extern "C" void kernel_launch(void* const* d_in, const int* in_sizes, int n_in,
                              void* d_out, int out_size, void* d_ws, size_t ws_size,
                              hipStream_t stream)
{
    const float* q_embed   = (const float*)d_in[0];
    const float* qa_embed  = (const float*)d_in[1];
    const float* conv_w    = (const float*)d_in[3];
    const float* conv_b    = (const float*)d_in[4];
    const float* sqrt_beta = (const float*)d_in[5];
    const float* sm_g      = (const float*)d_in[6];
    const float* sm_b      = (const float*)d_in[7];
    const float* k_w       = (const float*)d_in[8];
    const float* k_b       = (const float*)d_in[9];
    const float* v_w       = (const float*)d_in[10];
    const float* v_b       = (const float*)d_in[11];
    const float* out_w     = (const float*)d_in[12];
    const float* out_b     = (const float*)d_in[13];
    const float* gammas    = (const float*)d_in[14];
    const float* ln1_g     = (const float*)d_in[15];
    const float* ln1_b     = (const float*)d_in[16];
    const float* ff1_w     = (const float*)d_in[17];
    const float* ff1_b     = (const float*)d_in[18];
    const float* ff2_w     = (const float*)d_in[19];
    const float* ff2_b     = (const float*)d_in[20];
    const float* ln2_g     = (const float*)d_in[21];
    const float* ln2_b     = (const float*)d_in[22];

    const size_t NT = (size_t)M_ * D_;
    float* X = (float*)d_out;
    char* w = (char*)d_ws;
    float* Y  = (float*)w;  w += NT * 4;
    float* Qb = (float*)w;  w += NT * 4;
    float* Vb = (float*)w;  w += NT * 4;
    float* Fb = (float*)w;  w += NT * 4;
    float* Gb = (float*)w;                      // scores: 8*T*T f32 = 32 MB
    u16*  Hb  = (u16*)w;                        // aliases Gb: ffn hidden bf16 (32 MB)
    u16*  Xpad = (u16*)w;                       // aliases Gb during prep/conv
    u16*  Ypad = Xpad + (size_t)BSZ * TP_ * D_;
    u16*  W5t  = Ypad + (size_t)BSZ * TP_ * D_;
    w += (size_t)H_ * T_ * T_ * 4;
    u16* Xb  = (u16*)w; w += NT * 2;
    u16* Yb  = (u16*)w; w += NT * 2;
    u16* Cb  = (u16*)w; w += NT * 2;
    u16* KWt = (u16*)w; w += (size_t)6 * D_ * D_ * 2;
    u16* VWt = (u16*)w; w += (size_t)6 * D_ * D_ * 2;
    u16* OWt = (u16*)w; w += (size_t)6 * D_ * D_ * 2;
    u16* F1t = (u16*)w; w += (size_t)6 * D_ * FF_ * 2;
    u16* F2t = (u16*)w; w += (size_t)6 * FF_ * D_ * 2;

    dim3 blk(256);

    // ---- prep ----
    cast_pad<<<(BSZ * TP_ * D_ + 255) / 256, blk, 0, stream>>>(q_embed, qa_embed, Xpad, Ypad);
    w5_gather<<<(5 * D_ * D_ + 255) / 256, blk, 0, stream>>>(conv_w, W5t);
    transpose_bf16<<<dim3(D_ / 32, D_ / 32, 6), blk, 0, stream>>>(k_w, KWt, D_, D_);
    transpose_bf16<<<dim3(D_ / 32, D_ / 32, 6), blk, 0, stream>>>(v_w, VWt, D_, D_);
    transpose_bf16<<<dim3(D_ / 32, D_ / 32, 6), blk, 0, stream>>>(out_w, OWt, D_, D_);
    transpose_bf16<<<dim3(FF_ / 32, D_ / 32, 6), blk, 0, stream>>>(ff1_w, F1t, D_, FF_);
    transpose_bf16<<<dim3(D_ / 32, FF_ / 32, 6), blk, 0, stream>>>(ff2_w, F2t, FF_, D_);

    // ---- smooth(x), smooth(y) ----
    conv_mfma<<<dim3(4, 64), blk, 0, stream>>>(Xpad, W5t, Fb);
    smooth_ln<<<M_, blk, 0, stream>>>(q_embed, Fb, conv_b, sqrt_beta, sm_g, sm_b, X, Xb);
    conv_mfma<<<dim3(4, 64), blk, 0, stream>>>(Ypad, W5t, Fb);
    smooth_ln<<<M_, blk, 0, stream>>>(qa_embed, Fb, conv_b, sqrt_beta, sm_g, sm_b, Y, Yb);

    auto layer = [&](int l, int mtype, float* io, u16* iob, const u16* vinb, bool ffn) {
        gemm_mfma<<<dim3(4, 64), blk, 0, stream>>>(iob, KWt + (size_t)l * D_ * D_,
                                                   k_b + (size_t)l * D_, Qb, D_, D_, 0);
        gemm_mfma<<<dim3(4, 64), blk, 0, stream>>>(vinb, VWt + (size_t)l * D_ * D_,
                                                   v_b + (size_t)l * D_, Vb, D_, D_, 0);
        for (int b = 0; b < BSZ; ++b) {
            qk_kernel<<<dim3(16, 16, H_), blk, 0, stream>>>(Qb, Gb, b);
            decay_rows<<<dim3(T_, H_), blk, 0, stream>>>(Gb, gammas + l * H_, mtype);
            pv_kernel<<<dim3(16, H_), blk, 0, stream>>>(Gb, Vb, Cb, b);
        }
        gemm_mfma<<<dim3(4, 64), blk, 0, stream>>>(Cb, OWt + (size_t)l * D_ * D_,
                                                   out_b + (size_t)l * D_, Fb, D_, D_, 0);
        add_ln<<<M_, blk, 0, stream>>>(io, Fb, ln1_g + l * D_, ln1_b + l * D_, io, iob, 1e-5f);
        if (ffn) {
            gemm_mfma<<<dim3(16, 64), blk, 0, stream>>>(iob, F1t + (size_t)l * D_ * FF_,
                                                        ff1_b + (size_t)l * FF_, Hb, FF_, D_, 1);
            gemm_mfma<<<dim3(4, 64), blk, 0, stream>>>(Hb, F2t + (size_t)l * FF_ * D_,
                                                       ff2_b + (size_t)l * D_, Fb, D_, FF_, 0);
            add_ln<<<M_, blk, 0, stream>>>(io, Fb, ln2_g + l * D_, ln2_b + l * D_, io, iob, 1e-5f);
        }
    };

    layer(0, 1, Y, Yb, Yb, true);
    layer(1, 1, Y, Yb, Yb, true);
    layer(2, 1, X, Xb, Xb, false);
    layer(3, 0, X, Xb, Yb, true);
    layer(4, 1, X, Xb, Xb, false);
    layer(5, 0, X, Xb, Yb, true);
}

// Round 4
// 2452.165 us; speedup vs baseline: 7.3041x; 2.5710x over previous
//
#include <hip/hip_runtime.h>
#include <math.h>

#define T_  1024
#define D_  512
#define H_  8
#define DK_ 64
#define FF_ 2048
#define BSZ 8
#define M_  (BSZ * T_)   // 8192 rows
#define TP_ (T_ + 4)     // padded rows per batch for causal conv

typedef unsigned short u16;
typedef __attribute__((ext_vector_type(8))) __bf16 bf16x8;
typedef __attribute__((ext_vector_type(4))) float f32x4;

__device__ __forceinline__ u16 f2bf(float f) {            // RNE f32 -> bf16 bits
    unsigned int u = __float_as_uint(f);
    u += 0x7fffu + ((u >> 16) & 1u);
    return (u16)(u >> 16);
}
__device__ __forceinline__ float bf2f(u16 b) {
    return __uint_as_float((unsigned int)b << 16);
}

__device__ __forceinline__ void gload16(const void* g, void* l) {
    // async global->LDS, 16B/lane; LDS dest = wave-uniform base + lane*16
    __builtin_amdgcn_global_load_lds(
        (const __attribute__((address_space(1))) void*)g,
        (__attribute__((address_space(3))) void*)l, 16, 0, 0);
}

// ======================= bf16 MFMA GEMM (m97 structure) =======================
// C[M][N] = A[M][K](bf16) * Bt[N][K]^T(bf16) + bias. 128x128 tile, 4 waves.
// mode 0: f32 out; 1: bf16 out + relu; 2: bf16 out; 3: per-head-transposed
// bf16 out Vt[((b*H+h)*DK+dl)*T + t]  (for PV B-operand).
__global__ void __launch_bounds__(256) gemm_mfma(
    const u16* __restrict__ A, const u16* __restrict__ Bt,
    const float* __restrict__ bias, void* __restrict__ Cout,
    int N, int K, int mode)
{
    __shared__ __align__(16) u16 As[128 * 32];
    __shared__ __align__(16) u16 Bs[128 * 32];
    int tid = threadIdx.x;
    int wid = tid >> 6, lane = tid & 63;
    int quad = lane >> 4, mrow = lane & 15;
    int m0 = blockIdx.y * 128, n0 = blockIdx.x * 128;
    int wr = (wid >> 1) * 64, wc = (wid & 1) * 64;

    const u16* Ap = A + (size_t)(m0 + (tid >> 2)) * K + (tid & 3) * 8;
    const u16* Bp = Bt + (size_t)(n0 + (tid >> 2)) * K + (tid & 3) * 8;
    char* lA = (char*)As + wid * 1024;
    char* lB = (char*)Bs + wid * 1024;

    f32x4 acc[4][4] = {};
    for (int k0 = 0; k0 < K; k0 += 32) {
        __syncthreads();
        gload16(Ap + k0, lA);
        gload16(Ap + (size_t)64 * K + k0, lA + 4096);
        gload16(Bp + k0, lB);
        gload16(Bp + (size_t)64 * K + k0, lB + 4096);
        asm volatile("s_waitcnt vmcnt(0)" ::: "memory");
        __syncthreads();
        bf16x8 af[4], bf[4];
#pragma unroll
        for (int t = 0; t < 4; ++t) {
            af[t] = *(const bf16x8*)&As[(wr + t * 16 + mrow) * 32 + quad * 8];
            bf[t] = *(const bf16x8*)&Bs[(wc + t * 16 + mrow) * 32 + quad * 8];
        }
#pragma unroll
        for (int rt = 0; rt < 4; ++rt)
#pragma unroll
            for (int ct = 0; ct < 4; ++ct)
                acc[rt][ct] = __builtin_amdgcn_mfma_f32_16x16x32_bf16(
                    af[rt], bf[ct], acc[rt][ct], 0, 0, 0);
    }

#pragma unroll
    for (int ct = 0; ct < 4; ++ct) {
        int col = n0 + wc + ct * 16 + mrow;
        float bv = bias ? bias[col] : 0.f;
#pragma unroll
        for (int rt = 0; rt < 4; ++rt) {
            int rowb = m0 + wr + rt * 16 + quad * 4;
            if (mode == 0) {
                float* C = (float*)Cout;
#pragma unroll
                for (int e = 0; e < 4; ++e)
                    C[(size_t)(rowb + e) * N + col] = acc[rt][ct][e] + bv;
            } else if (mode == 1) {
                u16* C = (u16*)Cout;
#pragma unroll
                for (int e = 0; e < 4; ++e)
                    C[(size_t)(rowb + e) * N + col] = f2bf(fmaxf(acc[rt][ct][e] + bv, 0.f));
            } else if (mode == 2) {
                u16* C = (u16*)Cout;
#pragma unroll
                for (int e = 0; e < 4; ++e)
                    C[(size_t)(rowb + e) * N + col] = f2bf(acc[rt][ct][e] + bv);
            } else {
                u16* C = (u16*)Cout;
                int h = col >> 6, dl = col & 63;
#pragma unroll
                for (int e = 0; e < 4; ++e) {
                    int row = rowb + e;
                    int b = row >> 10, t = row & (T_ - 1);
                    C[(((size_t)(b * H_ + h) * DK_ + dl) << 10) + t] =
                        f2bf(acc[rt][ct][e] + bv);
                }
            }
        }
    }
}

// ======================= causal conv1d: 5 shifted MFMA passes =======================
__global__ void __launch_bounds__(256) conv_mfma(
    const u16* __restrict__ Xp, const u16* __restrict__ W5t, float* __restrict__ C)
{
    __shared__ __align__(16) u16 As[128 * 32];
    __shared__ __align__(16) u16 Bs[128 * 32];
    int tid = threadIdx.x;
    int wid = tid >> 6, lane = tid & 63;
    int quad = lane >> 4, mrow = lane & 15;
    int m0 = blockIdx.y * 128, n0 = blockIdx.x * 128;
    int wr = (wid >> 1) * 64, wc = (wid & 1) * 64;
    int b = m0 >> 10, tloc = m0 & (T_ - 1);

    const u16* Ap0 = Xp + (size_t)(b * TP_ + tloc + (tid >> 2)) * D_ + (tid & 3) * 8;
    const u16* Bp0 = W5t + (size_t)(n0 + (tid >> 2)) * D_ + (tid & 3) * 8;
    char* lA = (char*)As + wid * 1024;
    char* lB = (char*)Bs + wid * 1024;

    f32x4 acc[4][4] = {};
    for (int ks = 0; ks < 5; ++ks) {
        const u16* Ap = Ap0 + ks * D_;
        const u16* Bp = Bp0 + (size_t)ks * D_ * D_;
        for (int k0 = 0; k0 < D_; k0 += 32) {
            __syncthreads();
            gload16(Ap + k0, lA);
            gload16(Ap + (size_t)64 * D_ + k0, lA + 4096);
            gload16(Bp + k0, lB);
            gload16(Bp + (size_t)64 * D_ + k0, lB + 4096);
            asm volatile("s_waitcnt vmcnt(0)" ::: "memory");
            __syncthreads();
            bf16x8 af[4], bf[4];
#pragma unroll
            for (int t = 0; t < 4; ++t) {
                af[t] = *(const bf16x8*)&As[(wr + t * 16 + mrow) * 32 + quad * 8];
                bf[t] = *(const bf16x8*)&Bs[(wc + t * 16 + mrow) * 32 + quad * 8];
            }
#pragma unroll
            for (int rt = 0; rt < 4; ++rt)
#pragma unroll
                for (int ct = 0; ct < 4; ++ct)
                    acc[rt][ct] = __builtin_amdgcn_mfma_f32_16x16x32_bf16(
                        af[rt], bf[ct], acc[rt][ct], 0, 0, 0);
        }
    }
#pragma unroll
    for (int ct = 0; ct < 4; ++ct) {
        int col = n0 + wc + ct * 16 + mrow;
#pragma unroll
        for (int rt = 0; rt < 4; ++rt) {
            int row = m0 + wr + rt * 16 + quad * 4;
#pragma unroll
            for (int e = 0; e < 4; ++e)
                C[(size_t)(row + e) * D_ + col] = acc[rt][ct][e];
        }
    }
}

// ======================= QK^T MFMA: S[z][i][k] bf16, causal tiles =======================
// Qh: bf16 [B*T][D]. Both A and B operands are rows of Qh (kq_same).
__global__ void __launch_bounds__(256) qk_mfma(
    const u16* __restrict__ Qh, u16* __restrict__ S)
{
    int kt = blockIdx.x, it = blockIdx.y;
    if (kt > it) return;
    int z = blockIdx.z;
    int b = z >> 3, h = z & 7;
    __shared__ __align__(16) u16 As[64 * 32];
    __shared__ __align__(16) u16 Bs[64 * 32];
    int tid = threadIdx.x;
    int wid = tid >> 6, lane = tid & 63;
    int quad = lane >> 4, mrow = lane & 15;
    int wc = wid * 16;

    const u16* Ap = Qh + (size_t)(b * T_ + it * 64 + (tid >> 2)) * D_ + h * DK_ + (tid & 3) * 8;
    const u16* Bp = Qh + (size_t)(b * T_ + kt * 64 + (tid >> 2)) * D_ + h * DK_ + (tid & 3) * 8;
    char* lA = (char*)As + wid * 1024;
    char* lB = (char*)Bs + wid * 1024;

    f32x4 acc[4] = {};
#pragma unroll
    for (int k0 = 0; k0 < DK_; k0 += 32) {
        __syncthreads();
        gload16(Ap + k0, lA);
        gload16(Bp + k0, lB);
        asm volatile("s_waitcnt vmcnt(0)" ::: "memory");
        __syncthreads();
        bf16x8 af[4];
#pragma unroll
        for (int t = 0; t < 4; ++t)
            af[t] = *(const bf16x8*)&As[(t * 16 + mrow) * 32 + quad * 8];
        bf16x8 bf = *(const bf16x8*)&Bs[(wc + mrow) * 32 + quad * 8];
#pragma unroll
        for (int rt = 0; rt < 4; ++rt)
            acc[rt] = __builtin_amdgcn_mfma_f32_16x16x32_bf16(af[rt], bf, acc[rt], 0, 0, 0);
    }
    int col = kt * 64 + wc + mrow;
#pragma unroll
    for (int rt = 0; rt < 4; ++rt) {
        int row = it * 64 + rt * 16 + quad * 4;
#pragma unroll
        for (int e = 0; e < 4; ++e)
            S[((size_t)z * T_ + row + e) * T_ + col] = f2bf(acc[rt][e] * 0.125f);
    }
}

// ======================= per-row decay + double softmax (bf16 in-place S -> P) =======================
__global__ void __launch_bounds__(256) decay_rows(
    u16* __restrict__ S, const float* __restrict__ gam_l, int mtype)
{
    __shared__ float s_red[8];
    int i = blockIdx.x;
    int z = blockIdx.y;
    int h = z & 7;
    u16* row = S + ((size_t)z * T_ + i) * T_;
    int tid = threadIdx.x, lane = tid & 63, wid = tid >> 6;
    int kmax = (mtype == 0) ? (i - 1) : i;
    int wmax = i | 63;
    int k0 = tid * 4;

    if (kmax < 0) {
        if (k0 <= wmax) *(ushort4*)(row + k0) = make_ushort4(0, 0, 0, 0);
        return;
    }

    float sc[4];
    if (k0 + 3 <= kmax) {
        ushort4 v = *(const ushort4*)(row + k0);
        sc[0] = bf2f(v.x); sc[1] = bf2f(v.y); sc[2] = bf2f(v.z); sc[3] = bf2f(v.w);
    } else {
#pragma unroll
        for (int j = 0; j < 4; ++j)
            sc[j] = (k0 + j <= kmax) ? bf2f(row[k0 + j]) : -1e30f;
    }

    float mx = fmaxf(fmaxf(sc[0], sc[1]), fmaxf(sc[2], sc[3]));
    for (int o = 32; o > 0; o >>= 1) mx = fmaxf(mx, __shfl_xor(mx, o, 64));
    if (lane == 0) s_red[wid] = mx;
    __syncthreads();
    mx = fmaxf(fmaxf(s_red[0], s_red[1]), fmaxf(s_red[2], s_red[3]));
    __syncthreads();

    float p[4]; float ls = 0.f;
#pragma unroll
    for (int j = 0; j < 4; ++j) {
        p[j] = (k0 + j <= kmax) ? __expf(sc[j] - mx) : 0.f;
        ls += p[j];
    }
    float ssum = ls;
    for (int o = 32; o > 0; o >>= 1) ssum += __shfl_xor(ssum, o, 64);
    if (lane == 0) s_red[wid] = ssum;
    __syncthreads();
    float denom = s_red[0] + s_red[1] + s_red[2] + s_red[3];
    __syncthreads();
    float inv1 = 1.f / denom;
#pragma unroll
    for (int j = 0; j < 4; ++j) p[j] *= inv1;

    float tsum = p[0] + p[1] + p[2] + p[3];
    float incl = tsum;
    for (int o = 1; o < 64; o <<= 1) {
        float y = __shfl_up(incl, o, 64);
        if (lane >= o) incl += y;
    }
    if (lane == 63) s_red[wid] = incl;
    __syncthreads();
    float woff = 0.f;
    for (int w = 0; w < wid; ++w) woff += s_red[w];
    float total = s_red[0] + s_red[1] + s_red[2] + s_red[3];
    __syncthreads();
    float run = woff + incl - tsum;

    float gp = gam_l[h];
    float gam = -log1pf(__expf(gp));
#pragma unroll
    for (int j = 0; j < 4; ++j) {
        int k = k0 + j;
        run += p[j];
        float rem = total - run;
        if (rem < 0.f) rem = 0.f;
        float pos = fabsf((float)(k - i));
        float dist = sqrtf(rem * pos);
        float eff = __expf(dist * gam);
        eff = fminf(fmaxf(eff, 1e-5f), 1e5f);
        sc[j] = (k <= kmax) ? sc[j] * eff : -1e30f;
    }

    mx = fmaxf(fmaxf(sc[0], sc[1]), fmaxf(sc[2], sc[3]));
    for (int o = 32; o > 0; o >>= 1) mx = fmaxf(mx, __shfl_xor(mx, o, 64));
    if (lane == 0) s_red[wid] = mx;
    __syncthreads();
    mx = fmaxf(fmaxf(s_red[0], s_red[1]), fmaxf(s_red[2], s_red[3]));
    __syncthreads();
    ls = 0.f;
#pragma unroll
    for (int j = 0; j < 4; ++j) {
        p[j] = (k0 + j <= kmax) ? __expf(sc[j] - mx) : 0.f;
        ls += p[j];
    }
    ssum = ls;
    for (int o = 32; o > 0; o >>= 1) ssum += __shfl_xor(ssum, o, 64);
    if (lane == 0) s_red[wid] = ssum;
    __syncthreads();
    float denom2 = s_red[0] + s_red[1] + s_red[2] + s_red[3];
    float inv2 = 1.f / denom2;

    if (k0 <= wmax) {
        ushort4 v;
        v.x = f2bf(p[0] * inv2); v.y = f2bf(p[1] * inv2);
        v.z = f2bf(p[2] * inv2); v.w = f2bf(p[3] * inv2);
        *(ushort4*)(row + k0) = v;
    }
}

// ======================= PV MFMA: O = P(bf16) x V, causal K-bound =======================
// P: [z][T][T] bf16.  Vt: [bh][DK][T] bf16 (B-operand row-major over d).
// Out: bf16 concat [B*T][D].
__global__ void __launch_bounds__(256) pv_mfma(
    const u16* __restrict__ P, const u16* __restrict__ Vt,
    u16* __restrict__ O)
{
    int mt = blockIdx.x;
    int z = blockIdx.y;
    int b = z >> 3, h = z & 7;
    __shared__ __align__(16) u16 As[64 * 32];
    __shared__ __align__(16) u16 Bs[64 * 32];
    int tid = threadIdx.x;
    int wid = tid >> 6, lane = tid & 63;
    int quad = lane >> 4, mrow = lane & 15;
    int wc = wid * 16;

    const u16* Ap = P + ((size_t)z * T_ + mt * 64 + (tid >> 2)) * T_ + (tid & 3) * 8;
    const u16* Bp = Vt + ((size_t)z * DK_ + (tid >> 2)) * T_ + (tid & 3) * 8;
    char* lA = (char*)As + wid * 1024;
    char* lB = (char*)Bs + wid * 1024;

    int kend = (mt + 1) * 64;
    f32x4 acc[4] = {};
    for (int k0 = 0; k0 < kend; k0 += 32) {
        __syncthreads();
        gload16(Ap + k0, lA);
        gload16(Bp + k0, lB);
        asm volatile("s_waitcnt vmcnt(0)" ::: "memory");
        __syncthreads();
        bf16x8 af[4];
#pragma unroll
        for (int t = 0; t < 4; ++t)
            af[t] = *(const bf16x8*)&As[(t * 16 + mrow) * 32 + quad * 8];
        bf16x8 bf = *(const bf16x8*)&Bs[(wc + mrow) * 32 + quad * 8];
#pragma unroll
        for (int rt = 0; rt < 4; ++rt)
            acc[rt] = __builtin_amdgcn_mfma_f32_16x16x32_bf16(af[rt], bf, acc[rt], 0, 0, 0);
    }
    int col = h * DK_ + wc + mrow;
#pragma unroll
    for (int rt = 0; rt < 4; ++rt) {
        int row = b * T_ + mt * 64 + rt * 16 + quad * 4;
#pragma unroll
        for (int e = 0; e < 4; ++e)
            O[(size_t)(row + e) * D_ + col] = f2bf(acc[rt][e]);
    }
}

// ======================= prep kernels =======================
__global__ void __launch_bounds__(256) transpose_bf16(
    const float* __restrict__ W, u16* __restrict__ Wt, int K, int N)
{
    __shared__ float tile[32][33];
    size_t base = (size_t)blockIdx.z * K * N;
    W += base; Wt += base;
    int k0 = blockIdx.y * 32, n0 = blockIdx.x * 32;
    int r = threadIdx.x >> 3, c = (threadIdx.x & 7) * 4;
    float4 v = *(const float4*)(W + (size_t)(k0 + r) * N + n0 + c);
    tile[r][c] = v.x; tile[r][c + 1] = v.y; tile[r][c + 2] = v.z; tile[r][c + 3] = v.w;
    __syncthreads();
    ushort4 o;
    o.x = f2bf(tile[c + 0][r]); o.y = f2bf(tile[c + 1][r]);
    o.z = f2bf(tile[c + 2][r]); o.w = f2bf(tile[c + 3][r]);
    *(ushort4*)(Wt + (size_t)(n0 + r) * K + k0 + c) = o;
}

__global__ void w5_gather(const float* __restrict__ cw, u16* __restrict__ W5t)
{
    int idx = blockIdx.x * 256 + threadIdx.x;
    if (idx >= 5 * D_ * D_) return;
    int ks = idx / (D_ * D_);
    int rem = idx - ks * (D_ * D_);
    int o = rem >> 9, i = rem & (D_ - 1);
    W5t[idx] = f2bf(cw[((size_t)o * D_ + i) * 5 + ks]);
}

__global__ void cast_pad(const float* __restrict__ x, const float* __restrict__ y,
                         u16* __restrict__ Xp, u16* __restrict__ Yp)
{
    int idx = blockIdx.x * 256 + threadIdx.x;
    if (idx >= BSZ * TP_ * D_) return;
    int d = idx & (D_ - 1);
    int rowp = idx >> 9;
    int b = rowp / TP_;
    int t = rowp - b * TP_;
    u16 vx = 0, vy = 0;
    if (t >= 4) {
        size_t src = ((size_t)(b * T_ + t - 4) << 9) + d;
        vx = f2bf(x[src]); vy = f2bf(y[src]);
    }
    Xp[idx] = vx; Yp[idx] = vy;
}

// ======================= smooth pointwise + LayerNorm (eps=1e-12) =======================
__global__ void __launch_bounds__(256) smooth_ln(
    const float* __restrict__ x, const float* __restrict__ trend,
    const float* __restrict__ conv_b, const float* __restrict__ sqrt_beta,
    const float* __restrict__ g, const float* __restrict__ bb,
    float* __restrict__ out, u16* __restrict__ outb)
{
    __shared__ float s_red[8];
    int row = blockIdx.x, tid = threadIdx.x;
    int lane = tid & 63, wid = tid >> 6;
    float2 xv = ((const float2*)(x + (size_t)row * D_))[tid];
    float2 tv = ((const float2*)(trend + (size_t)row * D_))[tid];
    float2 cb = ((const float2*)conv_b)[tid];
    float2 sb = ((const float2*)sqrt_beta)[tid];
    float t0 = tv.x + cb.x, t1 = tv.y + cb.y;
    float v0 = t0 + sb.x * sb.x * (xv.x - t0) + xv.x;
    float v1 = t1 + sb.y * sb.y * (xv.y - t1) + xv.y;
    float s = v0 + v1, sq = v0 * v0 + v1 * v1;
    for (int o = 32; o > 0; o >>= 1) { s += __shfl_xor(s, o, 64); sq += __shfl_xor(sq, o, 64); }
    if (lane == 0) { s_red[wid] = s; s_red[4 + wid] = sq; }
    __syncthreads();
    s = s_red[0] + s_red[1] + s_red[2] + s_red[3];
    sq = s_red[4] + s_red[5] + s_red[6] + s_red[7];
    float mean = s * (1.f / D_);
    float var = sq * (1.f / D_) - mean * mean;
    if (var < 0.f) var = 0.f;
    float rstd = rsqrtf(var + 1e-12f);
    float2 gv = ((const float2*)g)[tid];
    float2 bv = ((const float2*)bb)[tid];
    float2 o2;
    o2.x = gv.x * (v0 - mean) * rstd + bv.x;
    o2.y = gv.y * (v1 - mean) * rstd + bv.y;
    ((float2*)(out + (size_t)row * D_))[tid] = o2;
    ushort2 ob; ob.x = f2bf(o2.x); ob.y = f2bf(o2.y);
    ((ushort2*)(outb + (size_t)row * D_))[tid] = ob;
}

// ======================= residual add + LayerNorm (f32 + bf16 out) =======================
__global__ void __launch_bounds__(256) add_ln(
    const float* __restrict__ a, const float* __restrict__ c,
    const float* __restrict__ g, const float* __restrict__ bb,
    float* __restrict__ out, u16* __restrict__ outb, float eps)
{
    __shared__ float s_red[8];
    int row = blockIdx.x, tid = threadIdx.x;
    int lane = tid & 63, wid = tid >> 6;
    float2 av = ((const float2*)(a + (size_t)row * D_))[tid];
    float2 cv = ((const float2*)(c + (size_t)row * D_))[tid];
    float v0 = av.x + cv.x;
    float v1 = av.y + cv.y;
    float s = v0 + v1, sq = v0 * v0 + v1 * v1;
    for (int o = 32; o > 0; o >>= 1) { s += __shfl_xor(s, o, 64); sq += __shfl_xor(sq, o, 64); }
    if (lane == 0) { s_red[wid] = s; s_red[4 + wid] = sq; }
    __syncthreads();
    s = s_red[0] + s_red[1] + s_red[2] + s_red[3];
    sq = s_red[4] + s_red[5] + s_red[6] + s_red[7];
    float mean = s * (1.f / D_);
    float var = sq * (1.f / D_) - mean * mean;
    if (var < 0.f) var = 0.f;
    float rstd = rsqrtf(var + eps);
    float2 gv = ((const float2*)g)[tid];
    float2 bv = ((const float2*)bb)[tid];
    float2 o2;
    o2.x = gv.x * (v0 - mean) * rstd + bv.x;
    o2.y = gv.y * (v1 - mean) * rstd + bv.y;
    ((float2*)(out + (size_t)row * D_))[tid] = o2;
    ushort2 ob; ob.x = f2bf(o2.x); ob.y = f2bf(o2.y);
    ((ushort2*)(outb + (size_t)row * D_))[tid] = ob;
}

// ======================= launch =======================
extern "C" void kernel_launch(void* const* d_in, const int* in_sizes, int n_in,
                              void* d_out, int out_size, void* d_ws, size_t ws_size,
                              hipStream_t stream)
{
    const float* q_embed   = (const float*)d_in[0];
    const float* qa_embed  = (const float*)d_in[1];
    const float* conv_w    = (const float*)d_in[3];
    const float* conv_b    = (const float*)d_in[4];
    const float* sqrt_beta = (const float*)d_in[5];
    const float* sm_g      = (const float*)d_in[6];
    const float* sm_b      = (const float*)d_in[7];
    const float* k_w       = (const float*)d_in[8];
    const float* k_b       = (const float*)d_in[9];
    const float* v_w       = (const float*)d_in[10];
    const float* v_b       = (const float*)d_in[11];
    const float* out_w     = (const float*)d_in[12];
    const float* out_b     = (const float*)d_in[13];
    const float* gammas    = (const float*)d_in[14];
    const float* ln1_g     = (const float*)d_in[15];
    const float* ln1_b     = (const float*)d_in[16];
    const float* ff1_w     = (const float*)d_in[17];
    const float* ff1_b     = (const float*)d_in[18];
    const float* ff2_w     = (const float*)d_in[19];
    const float* ff2_b     = (const float*)d_in[20];
    const float* ln2_g     = (const float*)d_in[21];
    const float* ln2_b     = (const float*)d_in[22];

    const size_t NT = (size_t)M_ * D_;
    float* X = (float*)d_out;
    char* w = (char*)d_ws;
    float* Y  = (float*)w; w += NT * 4;          // 16 MB
    float* Fb = (float*)w; w += NT * 4;          // 16 MB
    u16* Sb = (u16*)w;                           // scores/P bf16: 128 MB
    u16* Hb = Sb;                                // aliases: ffn hidden bf16 (32 MB)
    u16* Xpad = Sb;                              // aliases: prep buffers
    u16* Ypad = Xpad + (size_t)BSZ * TP_ * D_;
    u16* W5t  = Ypad + (size_t)BSZ * TP_ * D_;
    w += (size_t)BSZ * H_ * T_ * T_ * 2;
    u16* Xb  = (u16*)w; w += NT * 2;
    u16* Yb  = (u16*)w; w += NT * 2;
    u16* Cb  = (u16*)w; w += NT * 2;
    u16* Qh  = (u16*)w; w += NT * 2;
    u16* Vt  = (u16*)w; w += NT * 2;
    u16* KWt = (u16*)w; w += (size_t)6 * D_ * D_ * 2;
    u16* VWt = (u16*)w; w += (size_t)6 * D_ * D_ * 2;
    u16* OWt = (u16*)w; w += (size_t)6 * D_ * D_ * 2;
    u16* F1t = (u16*)w; w += (size_t)6 * D_ * FF_ * 2;
    u16* F2t = (u16*)w; w += (size_t)6 * FF_ * D_ * 2;

    dim3 blk(256);

    // ---- prep ----
    cast_pad<<<(BSZ * TP_ * D_ + 255) / 256, blk, 0, stream>>>(q_embed, qa_embed, Xpad, Ypad);
    w5_gather<<<(5 * D_ * D_ + 255) / 256, blk, 0, stream>>>(conv_w, W5t);
    transpose_bf16<<<dim3(D_ / 32, D_ / 32, 6), blk, 0, stream>>>(k_w, KWt, D_, D_);
    transpose_bf16<<<dim3(D_ / 32, D_ / 32, 6), blk, 0, stream>>>(v_w, VWt, D_, D_);
    transpose_bf16<<<dim3(D_ / 32, D_ / 32, 6), blk, 0, stream>>>(out_w, OWt, D_, D_);
    transpose_bf16<<<dim3(FF_ / 32, D_ / 32, 6), blk, 0, stream>>>(ff1_w, F1t, D_, FF_);
    transpose_bf16<<<dim3(D_ / 32, FF_ / 32, 6), blk, 0, stream>>>(ff2_w, F2t, FF_, D_);

    // ---- smooth(x), smooth(y) ----
    conv_mfma<<<dim3(4, 64), blk, 0, stream>>>(Xpad, W5t, Fb);
    smooth_ln<<<M_, blk, 0, stream>>>(q_embed, Fb, conv_b, sqrt_beta, sm_g, sm_b, X, Xb);
    conv_mfma<<<dim3(4, 64), blk, 0, stream>>>(Ypad, W5t, Fb);
    smooth_ln<<<M_, blk, 0, stream>>>(qa_embed, Fb, conv_b, sqrt_beta, sm_g, sm_b, Y, Yb);

    auto layer = [&](int l, int mtype, float* io, u16* iob, const u16* vinb, bool ffn) {
        gemm_mfma<<<dim3(4, 64), blk, 0, stream>>>(iob, KWt + (size_t)l * D_ * D_,
                                                   k_b + (size_t)l * D_, Qh, D_, D_, 2);
        gemm_mfma<<<dim3(4, 64), blk, 0, stream>>>(vinb, VWt + (size_t)l * D_ * D_,
                                                   v_b + (size_t)l * D_, Vt, D_, D_, 3);
        qk_mfma<<<dim3(16, 16, 64), blk, 0, stream>>>(Qh, Sb);
        decay_rows<<<dim3(T_, 64), blk, 0, stream>>>(Sb, gammas + l * H_, mtype);
        pv_mfma<<<dim3(16, 64), blk, 0, stream>>>(Sb, Vt, Cb);
        gemm_mfma<<<dim3(4, 64), blk, 0, stream>>>(Cb, OWt + (size_t)l * D_ * D_,
                                                   out_b + (size_t)l * D_, Fb, D_, D_, 0);
        add_ln<<<M_, blk, 0, stream>>>(io, Fb, ln1_g + l * D_, ln1_b + l * D_, io, iob, 1e-5f);
        if (ffn) {
            gemm_mfma<<<dim3(16, 64), blk, 0, stream>>>(iob, F1t + (size_t)l * D_ * FF_,
                                                        ff1_b + (size_t)l * FF_, Hb, FF_, D_, 1);
            gemm_mfma<<<dim3(4, 64), blk, 0, stream>>>(Hb, F2t + (size_t)l * FF_ * D_,
                                                       ff2_b + (size_t)l * D_, Fb, D_, FF_, 0);
            add_ln<<<M_, blk, 0, stream>>>(io, Fb, ln2_g + l * D_, ln2_b + l * D_, io, iob, 1e-5f);
        }
    };

    layer(0, 1, Y, Yb, Yb, true);
    layer(1, 1, Y, Yb, Yb, true);
    layer(2, 1, X, Xb, Xb, false);
    layer(3, 0, X, Xb, Yb, true);
    layer(4, 1, X, Xb, Xb, false);
    layer(5, 0, X, Xb, Yb, true);
}

// Round 5
// 2225.932 us; speedup vs baseline: 8.0465x; 1.1016x over previous
//
#include <hip/hip_runtime.h>
#include <math.h>

#define T_  1024
#define D_  512
#define H_  8
#define DK_ 64
#define FF_ 2048
#define BSZ 8
#define M_  (BSZ * T_)   // 8192 rows
#define TP_ (T_ + 4)     // padded rows per batch for causal conv

typedef unsigned short u16;
typedef __attribute__((ext_vector_type(8))) __bf16 bf16x8;
typedef __attribute__((ext_vector_type(4))) float f32x4;

__device__ __forceinline__ u16 f2bf(float f) {            // RNE f32 -> bf16 bits
    unsigned int u = __float_as_uint(f);
    u += 0x7fffu + ((u >> 16) & 1u);
    return (u16)(u >> 16);
}
__device__ __forceinline__ float bf2f(u16 b) {
    return __uint_as_float((unsigned int)b << 16);
}

__device__ __forceinline__ void gload16(const void* g, void* l) {
    // async global->LDS, 16B/lane; LDS dest = wave-uniform base + lane*16
    __builtin_amdgcn_global_load_lds(
        (const __attribute__((address_space(1))) void*)g,
        (__attribute__((address_space(3))) void*)l, 16, 0, 0);
}

// ======================= bf16 MFMA GEMM (m97 structure) =======================
// C[M][N] = A[M][K](bf16) * Bt[N][K]^T(bf16) + bias. 128x128 tile, 4 waves.
// mode 0: f32 out; 1: bf16 out + relu; 2: bf16 out; 3: per-head-transposed
// bf16 out Vt[((b*H+h)*DK+dl)*T + t]  (for PV B-operand).
__global__ void __launch_bounds__(256) gemm_mfma(
    const u16* __restrict__ A, const u16* __restrict__ Bt,
    const float* __restrict__ bias, void* __restrict__ Cout,
    int N, int K, int mode)
{
    __shared__ __align__(16) u16 As[128 * 32];
    __shared__ __align__(16) u16 Bs[128 * 32];
    int tid = threadIdx.x;
    int wid = tid >> 6, lane = tid & 63;
    int quad = lane >> 4, mrow = lane & 15;
    int m0 = blockIdx.y * 128, n0 = blockIdx.x * 128;
    int wr = (wid >> 1) * 64, wc = (wid & 1) * 64;

    const u16* Ap = A + (size_t)(m0 + (tid >> 2)) * K + (tid & 3) * 8;
    const u16* Bp = Bt + (size_t)(n0 + (tid >> 2)) * K + (tid & 3) * 8;
    char* lA = (char*)As + wid * 1024;
    char* lB = (char*)Bs + wid * 1024;

    f32x4 acc[4][4] = {};
    for (int k0 = 0; k0 < K; k0 += 32) {
        __syncthreads();
        gload16(Ap + k0, lA);
        gload16(Ap + (size_t)64 * K + k0, lA + 4096);
        gload16(Bp + k0, lB);
        gload16(Bp + (size_t)64 * K + k0, lB + 4096);
        asm volatile("s_waitcnt vmcnt(0)" ::: "memory");
        __syncthreads();
        bf16x8 af[4], bf[4];
#pragma unroll
        for (int t = 0; t < 4; ++t) {
            af[t] = *(const bf16x8*)&As[(wr + t * 16 + mrow) * 32 + quad * 8];
            bf[t] = *(const bf16x8*)&Bs[(wc + t * 16 + mrow) * 32 + quad * 8];
        }
#pragma unroll
        for (int rt = 0; rt < 4; ++rt)
#pragma unroll
            for (int ct = 0; ct < 4; ++ct)
                acc[rt][ct] = __builtin_amdgcn_mfma_f32_16x16x32_bf16(
                    af[rt], bf[ct], acc[rt][ct], 0, 0, 0);
    }

#pragma unroll
    for (int ct = 0; ct < 4; ++ct) {
        int col = n0 + wc + ct * 16 + mrow;
        float bv = bias ? bias[col] : 0.f;
#pragma unroll
        for (int rt = 0; rt < 4; ++rt) {
            int rowb = m0 + wr + rt * 16 + quad * 4;
            if (mode == 0) {
                float* C = (float*)Cout;
#pragma unroll
                for (int e = 0; e < 4; ++e)
                    C[(size_t)(rowb + e) * N + col] = acc[rt][ct][e] + bv;
            } else if (mode == 1) {
                u16* C = (u16*)Cout;
#pragma unroll
                for (int e = 0; e < 4; ++e)
                    C[(size_t)(rowb + e) * N + col] = f2bf(fmaxf(acc[rt][ct][e] + bv, 0.f));
            } else if (mode == 2) {
                u16* C = (u16*)Cout;
#pragma unroll
                for (int e = 0; e < 4; ++e)
                    C[(size_t)(rowb + e) * N + col] = f2bf(acc[rt][ct][e] + bv);
            } else {
                u16* C = (u16*)Cout;
                int h = col >> 6, dl = col & 63;
#pragma unroll
                for (int e = 0; e < 4; ++e) {
                    int row = rowb + e;
                    int b = row >> 10, t = row & (T_ - 1);
                    C[(((size_t)(b * H_ + h) * DK_ + dl) << 10) + t] =
                        f2bf(acc[rt][ct][e] + bv);
                }
            }
        }
    }
}

// ======================= causal conv1d: 5 shifted MFMA passes =======================
__global__ void __launch_bounds__(256) conv_mfma(
    const u16* __restrict__ Xp, const u16* __restrict__ W5t, float* __restrict__ C)
{
    __shared__ __align__(16) u16 As[128 * 32];
    __shared__ __align__(16) u16 Bs[128 * 32];
    int tid = threadIdx.x;
    int wid = tid >> 6, lane = tid & 63;
    int quad = lane >> 4, mrow = lane & 15;
    int m0 = blockIdx.y * 128, n0 = blockIdx.x * 128;
    int wr = (wid >> 1) * 64, wc = (wid & 1) * 64;
    int b = m0 >> 10, tloc = m0 & (T_ - 1);

    const u16* Ap0 = Xp + (size_t)(b * TP_ + tloc + (tid >> 2)) * D_ + (tid & 3) * 8;
    const u16* Bp0 = W5t + (size_t)(n0 + (tid >> 2)) * D_ + (tid & 3) * 8;
    char* lA = (char*)As + wid * 1024;
    char* lB = (char*)Bs + wid * 1024;

    f32x4 acc[4][4] = {};
    for (int ks = 0; ks < 5; ++ks) {
        const u16* Ap = Ap0 + ks * D_;
        const u16* Bp = Bp0 + (size_t)ks * D_ * D_;
        for (int k0 = 0; k0 < D_; k0 += 32) {
            __syncthreads();
            gload16(Ap + k0, lA);
            gload16(Ap + (size_t)64 * D_ + k0, lA + 4096);
            gload16(Bp + k0, lB);
            gload16(Bp + (size_t)64 * D_ + k0, lB + 4096);
            asm volatile("s_waitcnt vmcnt(0)" ::: "memory");
            __syncthreads();
            bf16x8 af[4], bf[4];
#pragma unroll
            for (int t = 0; t < 4; ++t) {
                af[t] = *(const bf16x8*)&As[(wr + t * 16 + mrow) * 32 + quad * 8];
                bf[t] = *(const bf16x8*)&Bs[(wc + t * 16 + mrow) * 32 + quad * 8];
            }
#pragma unroll
            for (int rt = 0; rt < 4; ++rt)
#pragma unroll
                for (int ct = 0; ct < 4; ++ct)
                    acc[rt][ct] = __builtin_amdgcn_mfma_f32_16x16x32_bf16(
                        af[rt], bf[ct], acc[rt][ct], 0, 0, 0);
        }
    }
#pragma unroll
    for (int ct = 0; ct < 4; ++ct) {
        int col = n0 + wc + ct * 16 + mrow;
#pragma unroll
        for (int rt = 0; rt < 4; ++rt) {
            int row = m0 + wr + rt * 16 + quad * 4;
#pragma unroll
            for (int e = 0; e < 4; ++e)
                C[(size_t)(row + e) * D_ + col] = acc[rt][ct][e];
        }
    }
}

// ======================= QK^T MFMA: S[z][i][k] bf16, causal tiles =======================
__global__ void __launch_bounds__(256) qk_mfma(
    const u16* __restrict__ Qh, u16* __restrict__ S)
{
    int kt = blockIdx.x, it = blockIdx.y;
    if (kt > it) return;
    int z = blockIdx.z;
    int b = z >> 3, h = z & 7;
    __shared__ __align__(16) u16 As[64 * 32];
    __shared__ __align__(16) u16 Bs[64 * 32];
    int tid = threadIdx.x;
    int wid = tid >> 6, lane = tid & 63;
    int quad = lane >> 4, mrow = lane & 15;
    int wc = wid * 16;

    const u16* Ap = Qh + (size_t)(b * T_ + it * 64 + (tid >> 2)) * D_ + h * DK_ + (tid & 3) * 8;
    const u16* Bp = Qh + (size_t)(b * T_ + kt * 64 + (tid >> 2)) * D_ + h * DK_ + (tid & 3) * 8;
    char* lA = (char*)As + wid * 1024;
    char* lB = (char*)Bs + wid * 1024;

    f32x4 acc[4] = {};
#pragma unroll
    for (int k0 = 0; k0 < DK_; k0 += 32) {
        __syncthreads();
        gload16(Ap + k0, lA);
        gload16(Bp + k0, lB);
        asm volatile("s_waitcnt vmcnt(0)" ::: "memory");
        __syncthreads();
        bf16x8 af[4];
#pragma unroll
        for (int t = 0; t < 4; ++t)
            af[t] = *(const bf16x8*)&As[(t * 16 + mrow) * 32 + quad * 8];
        bf16x8 bf = *(const bf16x8*)&Bs[(wc + mrow) * 32 + quad * 8];
#pragma unroll
        for (int rt = 0; rt < 4; ++rt)
            acc[rt] = __builtin_amdgcn_mfma_f32_16x16x32_bf16(af[rt], bf, acc[rt], 0, 0, 0);
    }
    int col = kt * 64 + wc + mrow;
#pragma unroll
    for (int rt = 0; rt < 4; ++rt) {
        int row = it * 64 + rt * 16 + quad * 4;
#pragma unroll
        for (int e = 0; e < 4; ++e)
            S[((size_t)z * T_ + row + e) * T_ + col] = f2bf(acc[rt][e] * 0.125f);
    }
}

// ======================= per-row decay + double softmax, one WAVE per row =======================
// Strided layout: lane handles k = c*64 + lane. Work ∝ row length. No LDS/barriers.
__global__ void __launch_bounds__(256) decay_rows(
    u16* __restrict__ S, const float* __restrict__ gam_l, int mtype)
{
    int tid = threadIdx.x;
    int wv = tid >> 6, lane = tid & 63;
    int i = blockIdx.x * 4 + wv;
    int z = blockIdx.y;
    int h = z & 7;
    u16* row = S + ((size_t)z * T_ + i) * T_;
    int kmax = (mtype == 0) ? (i - 1) : i;
    int cw = (i >> 6) + 1;              // chunks the PV tile will read

    if (kmax < 0) {                     // mtype==0, i==0 (zero_pad row)
        for (int c = 0; c < cw; ++c) row[c * 64 + lane] = 0;
        return;
    }
    int nc = (kmax >> 6) + 1;           // active chunks (nc <= cw <= 16)

    float sc[16], p[16];
    // ---- load + row max ----
    float mx = -1e30f;
    for (int c = 0; c < nc; ++c) {
        int k = c * 64 + lane;
        float v = (k <= kmax) ? bf2f(row[k]) : -1e30f;
        sc[c] = v;
        mx = fmaxf(mx, v);
    }
#pragma unroll
    for (int o = 32; o > 0; o >>= 1) mx = fmaxf(mx, __shfl_xor(mx, o, 64));

    // ---- softmax #1 (unnormalized) ----
    float tot = 0.f;
    for (int c = 0; c < nc; ++c) {
        float e = (c * 64 + lane <= kmax) ? __expf(sc[c] - mx) : 0.f;
        p[c] = e;
        tot += e;
    }
#pragma unroll
    for (int o = 32; o > 0; o >>= 1) tot += __shfl_xor(tot, o, 64);
    float inv1 = 1.f / tot;

    // ---- cumsum + distance effect (normalization folded into inv1) ----
    float gp = gam_l[h];
    float gam = -log1pf(__expf(gp));
    float fi = (float)i;
    float running = 0.f;
    for (int c = 0; c < nc; ++c) {
        float pref = p[c];
#pragma unroll
        for (int o = 1; o < 64; o <<= 1) {
            float y = __shfl_up(pref, o, 64);
            if (lane >= o) pref += y;
        }
        float incl = running + pref;
        running += __shfl(pref, 63, 64);
        int k = c * 64 + lane;
        float rem = (tot - incl) * inv1;
        if (rem < 0.f) rem = 0.f;
        float pos = fabsf((float)k - fi);
        float dist = sqrtf(rem * pos);
        float eff = __expf(dist * gam);
        eff = fminf(fmaxf(eff, 1e-5f), 1e5f);
        sc[c] = (k <= kmax) ? sc[c] * eff : -1e30f;
    }

    // ---- softmax #2 ----
    float mx2 = -1e30f;
    for (int c = 0; c < nc; ++c) mx2 = fmaxf(mx2, sc[c]);
#pragma unroll
    for (int o = 32; o > 0; o >>= 1) mx2 = fmaxf(mx2, __shfl_xor(mx2, o, 64));
    float tot2 = 0.f;
    for (int c = 0; c < nc; ++c) {
        float e = (c * 64 + lane <= kmax) ? __expf(sc[c] - mx2) : 0.f;
        p[c] = e;
        tot2 += e;
    }
#pragma unroll
    for (int o = 32; o > 0; o >>= 1) tot2 += __shfl_xor(tot2, o, 64);
    float inv2 = 1.f / tot2;

    // ---- write P (zero-fill masked + tail chunks the PV tile reads) ----
    for (int c = 0; c < nc; ++c)
        row[c * 64 + lane] = f2bf(p[c] * inv2);
    for (int c = nc; c < cw; ++c)
        row[c * 64 + lane] = 0;
}

// ======================= PV MFMA: O = P(bf16) x V, causal K-bound =======================
__global__ void __launch_bounds__(256) pv_mfma(
    const u16* __restrict__ P, const u16* __restrict__ Vt,
    u16* __restrict__ O)
{
    int mt = blockIdx.x;
    int z = blockIdx.y;
    int b = z >> 3, h = z & 7;
    __shared__ __align__(16) u16 As[64 * 32];
    __shared__ __align__(16) u16 Bs[64 * 32];
    int tid = threadIdx.x;
    int wid = tid >> 6, lane = tid & 63;
    int quad = lane >> 4, mrow = lane & 15;
    int wc = wid * 16;

    const u16* Ap = P + ((size_t)z * T_ + mt * 64 + (tid >> 2)) * T_ + (tid & 3) * 8;
    const u16* Bp = Vt + ((size_t)z * DK_ + (tid >> 2)) * T_ + (tid & 3) * 8;
    char* lA = (char*)As + wid * 1024;
    char* lB = (char*)Bs + wid * 1024;

    int kend = (mt + 1) * 64;
    f32x4 acc[4] = {};
    for (int k0 = 0; k0 < kend; k0 += 32) {
        __syncthreads();
        gload16(Ap + k0, lA);
        gload16(Bp + k0, lB);
        asm volatile("s_waitcnt vmcnt(0)" ::: "memory");
        __syncthreads();
        bf16x8 af[4];
#pragma unroll
        for (int t = 0; t < 4; ++t)
            af[t] = *(const bf16x8*)&As[(t * 16 + mrow) * 32 + quad * 8];
        bf16x8 bf = *(const bf16x8*)&Bs[(wc + mrow) * 32 + quad * 8];
#pragma unroll
        for (int rt = 0; rt < 4; ++rt)
            acc[rt] = __builtin_amdgcn_mfma_f32_16x16x32_bf16(af[rt], bf, acc[rt], 0, 0, 0);
    }
    int col = h * DK_ + wc + mrow;
#pragma unroll
    for (int rt = 0; rt < 4; ++rt) {
        int row = b * T_ + mt * 64 + rt * 16 + quad * 4;
#pragma unroll
        for (int e = 0; e < 4; ++e)
            O[(size_t)(row + e) * D_ + col] = f2bf(acc[rt][e]);
    }
}

// ======================= prep kernels =======================
__global__ void __launch_bounds__(256) transpose_bf16(
    const float* __restrict__ W, u16* __restrict__ Wt, int K, int N)
{
    __shared__ float tile[32][33];
    size_t base = (size_t)blockIdx.z * K * N;
    W += base; Wt += base;
    int k0 = blockIdx.y * 32, n0 = blockIdx.x * 32;
    int r = threadIdx.x >> 3, c = (threadIdx.x & 7) * 4;
    float4 v = *(const float4*)(W + (size_t)(k0 + r) * N + n0 + c);
    tile[r][c] = v.x; tile[r][c + 1] = v.y; tile[r][c + 2] = v.z; tile[r][c + 3] = v.w;
    __syncthreads();
    ushort4 o;
    o.x = f2bf(tile[c + 0][r]); o.y = f2bf(tile[c + 1][r]);
    o.z = f2bf(tile[c + 2][r]); o.w = f2bf(tile[c + 3][r]);
    *(ushort4*)(Wt + (size_t)(n0 + r) * K + k0 + c) = o;
}

__global__ void w5_gather(const float* __restrict__ cw, u16* __restrict__ W5t)
{
    int idx = blockIdx.x * 256 + threadIdx.x;
    if (idx >= 5 * D_ * D_) return;
    int ks = idx / (D_ * D_);
    int rem = idx - ks * (D_ * D_);
    int o = rem >> 9, i = rem & (D_ - 1);
    W5t[idx] = f2bf(cw[((size_t)o * D_ + i) * 5 + ks]);
}

__global__ void cast_pad(const float* __restrict__ x, const float* __restrict__ y,
                         u16* __restrict__ Xp, u16* __restrict__ Yp)
{
    int idx = blockIdx.x * 256 + threadIdx.x;
    if (idx >= BSZ * TP_ * D_) return;
    int d = idx & (D_ - 1);
    int rowp = idx >> 9;
    int b = rowp / TP_;
    int t = rowp - b * TP_;
    u16 vx = 0, vy = 0;
    if (t >= 4) {
        size_t src = ((size_t)(b * T_ + t - 4) << 9) + d;
        vx = f2bf(x[src]); vy = f2bf(y[src]);
    }
    Xp[idx] = vx; Yp[idx] = vy;
}

// ======================= smooth pointwise + LayerNorm (eps=1e-12) =======================
__global__ void __launch_bounds__(256) smooth_ln(
    const float* __restrict__ x, const float* __restrict__ trend,
    const float* __restrict__ conv_b, const float* __restrict__ sqrt_beta,
    const float* __restrict__ g, const float* __restrict__ bb,
    float* __restrict__ out, u16* __restrict__ outb)
{
    __shared__ float s_red[8];
    int row = blockIdx.x, tid = threadIdx.x;
    int lane = tid & 63, wid = tid >> 6;
    float2 xv = ((const float2*)(x + (size_t)row * D_))[tid];
    float2 tv = ((const float2*)(trend + (size_t)row * D_))[tid];
    float2 cb = ((const float2*)conv_b)[tid];
    float2 sb = ((const float2*)sqrt_beta)[tid];
    float t0 = tv.x + cb.x, t1 = tv.y + cb.y;
    float v0 = t0 + sb.x * sb.x * (xv.x - t0) + xv.x;
    float v1 = t1 + sb.y * sb.y * (xv.y - t1) + xv.y;
    float s = v0 + v1, sq = v0 * v0 + v1 * v1;
    for (int o = 32; o > 0; o >>= 1) { s += __shfl_xor(s, o, 64); sq += __shfl_xor(sq, o, 64); }
    if (lane == 0) { s_red[wid] = s; s_red[4 + wid] = sq; }
    __syncthreads();
    s = s_red[0] + s_red[1] + s_red[2] + s_red[3];
    sq = s_red[4] + s_red[5] + s_red[6] + s_red[7];
    float mean = s * (1.f / D_);
    float var = sq * (1.f / D_) - mean * mean;
    if (var < 0.f) var = 0.f;
    float rstd = rsqrtf(var + 1e-12f);
    float2 gv = ((const float2*)g)[tid];
    float2 bv = ((const float2*)bb)[tid];
    float2 o2;
    o2.x = gv.x * (v0 - mean) * rstd + bv.x;
    o2.y = gv.y * (v1 - mean) * rstd + bv.y;
    ((float2*)(out + (size_t)row * D_))[tid] = o2;
    ushort2 ob; ob.x = f2bf(o2.x); ob.y = f2bf(o2.y);
    ((ushort2*)(outb + (size_t)row * D_))[tid] = ob;
}

// ======================= residual add + LayerNorm (f32 + bf16 out) =======================
__global__ void __launch_bounds__(256) add_ln(
    const float* __restrict__ a, const float* __restrict__ c,
    const float* __restrict__ g, const float* __restrict__ bb,
    float* __restrict__ out, u16* __restrict__ outb, float eps)
{
    __shared__ float s_red[8];
    int row = blockIdx.x, tid = threadIdx.x;
    int lane = tid & 63, wid = tid >> 6;
    float2 av = ((const float2*)(a + (size_t)row * D_))[tid];
    float2 cv = ((const float2*)(c + (size_t)row * D_))[tid];
    float v0 = av.x + cv.x;
    float v1 = av.y + cv.y;
    float s = v0 + v1, sq = v0 * v0 + v1 * v1;
    for (int o = 32; o > 0; o >>= 1) { s += __shfl_xor(s, o, 64); sq += __shfl_xor(sq, o, 64); }
    if (lane == 0) { s_red[wid] = s; s_red[4 + wid] = sq; }
    __syncthreads();
    s = s_red[0] + s_red[1] + s_red[2] + s_red[3];
    sq = s_red[4] + s_red[5] + s_red[6] + s_red[7];
    float mean = s * (1.f / D_);
    float var = sq * (1.f / D_) - mean * mean;
    if (var < 0.f) var = 0.f;
    float rstd = rsqrtf(var + eps);
    float2 gv = ((const float2*)g)[tid];
    float2 bv = ((const float2*)bb)[tid];
    float2 o2;
    o2.x = gv.x * (v0 - mean) * rstd + bv.x;
    o2.y = gv.y * (v1 - mean) * rstd + bv.y;
    ((float2*)(out + (size_t)row * D_))[tid] = o2;
    ushort2 ob; ob.x = f2bf(o2.x); ob.y = f2bf(o2.y);
    ((ushort2*)(outb + (size_t)row * D_))[tid] = ob;
}

// ======================= launch =======================
extern "C" void kernel_launch(void* const* d_in, const int* in_sizes, int n_in,
                              void* d_out, int out_size, void* d_ws, size_t ws_size,
                              hipStream_t stream)
{
    const float* q_embed   = (const float*)d_in[0];
    const float* qa_embed  = (const float*)d_in[1];
    const float* conv_w    = (const float*)d_in[3];
    const float* conv_b    = (const float*)d_in[4];
    const float* sqrt_beta = (const float*)d_in[5];
    const float* sm_g      = (const float*)d_in[6];
    const float* sm_b      = (const float*)d_in[7];
    const float* k_w       = (const float*)d_in[8];
    const float* k_b       = (const float*)d_in[9];
    const float* v_w       = (const float*)d_in[10];
    const float* v_b       = (const float*)d_in[11];
    const float* out_w     = (const float*)d_in[12];
    const float* out_b     = (const float*)d_in[13];
    const float* gammas    = (const float*)d_in[14];
    const float* ln1_g     = (const float*)d_in[15];
    const float* ln1_b     = (const float*)d_in[16];
    const float* ff1_w     = (const float*)d_in[17];
    const float* ff1_b     = (const float*)d_in[18];
    const float* ff2_w     = (const float*)d_in[19];
    const float* ff2_b     = (const float*)d_in[20];
    const float* ln2_g     = (const float*)d_in[21];
    const float* ln2_b     = (const float*)d_in[22];

    const size_t NT = (size_t)M_ * D_;
    float* X = (float*)d_out;
    char* w = (char*)d_ws;
    float* Y  = (float*)w; w += NT * 4;          // 16 MB
    float* Fb = (float*)w; w += NT * 4;          // 16 MB
    u16* Sb = (u16*)w;                           // scores/P bf16: 128 MB
    u16* Hb = Sb;                                // aliases: ffn hidden bf16 (32 MB)
    u16* Xpad = Sb;                              // aliases: prep buffers
    u16* Ypad = Xpad + (size_t)BSZ * TP_ * D_;
    u16* W5t  = Ypad + (size_t)BSZ * TP_ * D_;
    w += (size_t)BSZ * H_ * T_ * T_ * 2;
    u16* Xb  = (u16*)w; w += NT * 2;
    u16* Yb  = (u16*)w; w += NT * 2;
    u16* Cb  = (u16*)w; w += NT * 2;
    u16* Qh  = (u16*)w; w += NT * 2;
    u16* Vt  = (u16*)w; w += NT * 2;
    u16* KWt = (u16*)w; w += (size_t)6 * D_ * D_ * 2;
    u16* VWt = (u16*)w; w += (size_t)6 * D_ * D_ * 2;
    u16* OWt = (u16*)w; w += (size_t)6 * D_ * D_ * 2;
    u16* F1t = (u16*)w; w += (size_t)6 * D_ * FF_ * 2;
    u16* F2t = (u16*)w; w += (size_t)6 * FF_ * D_ * 2;

    dim3 blk(256);

    // ---- prep ----
    cast_pad<<<(BSZ * TP_ * D_ + 255) / 256, blk, 0, stream>>>(q_embed, qa_embed, Xpad, Ypad);
    w5_gather<<<(5 * D_ * D_ + 255) / 256, blk, 0, stream>>>(conv_w, W5t);
    transpose_bf16<<<dim3(D_ / 32, D_ / 32, 6), blk, 0, stream>>>(k_w, KWt, D_, D_);
    transpose_bf16<<<dim3(D_ / 32, D_ / 32, 6), blk, 0, stream>>>(v_w, VWt, D_, D_);
    transpose_bf16<<<dim3(D_ / 32, D_ / 32, 6), blk, 0, stream>>>(out_w, OWt, D_, D_);
    transpose_bf16<<<dim3(FF_ / 32, D_ / 32, 6), blk, 0, stream>>>(ff1_w, F1t, D_, FF_);
    transpose_bf16<<<dim3(D_ / 32, FF_ / 32, 6), blk, 0, stream>>>(ff2_w, F2t, FF_, D_);

    // ---- smooth(x), smooth(y) ----
    conv_mfma<<<dim3(4, 64), blk, 0, stream>>>(Xpad, W5t, Fb);
    smooth_ln<<<M_, blk, 0, stream>>>(q_embed, Fb, conv_b, sqrt_beta, sm_g, sm_b, X, Xb);
    conv_mfma<<<dim3(4, 64), blk, 0, stream>>>(Ypad, W5t, Fb);
    smooth_ln<<<M_, blk, 0, stream>>>(qa_embed, Fb, conv_b, sqrt_beta, sm_g, sm_b, Y, Yb);

    auto layer = [&](int l, int mtype, float* io, u16* iob, const u16* vinb, bool ffn) {
        gemm_mfma<<<dim3(4, 64), blk, 0, stream>>>(iob, KWt + (size_t)l * D_ * D_,
                                                   k_b + (size_t)l * D_, Qh, D_, D_, 2);
        gemm_mfma<<<dim3(4, 64), blk, 0, stream>>>(vinb, VWt + (size_t)l * D_ * D_,
                                                   v_b + (size_t)l * D_, Vt, D_, D_, 3);
        qk_mfma<<<dim3(16, 16, 64), blk, 0, stream>>>(Qh, Sb);
        decay_rows<<<dim3(T_ / 4, 64), blk, 0, stream>>>(Sb, gammas + l * H_, mtype);
        pv_mfma<<<dim3(16, 64), blk, 0, stream>>>(Sb, Vt, Cb);
        gemm_mfma<<<dim3(4, 64), blk, 0, stream>>>(Cb, OWt + (size_t)l * D_ * D_,
                                                   out_b + (size_t)l * D_, Fb, D_, D_, 0);
        add_ln<<<M_, blk, 0, stream>>>(io, Fb, ln1_g + l * D_, ln1_b + l * D_, io, iob, 1e-5f);
        if (ffn) {
            gemm_mfma<<<dim3(16, 64), blk, 0, stream>>>(iob, F1t + (size_t)l * D_ * FF_,
                                                        ff1_b + (size_t)l * FF_, Hb, FF_, D_, 1);
            gemm_mfma<<<dim3(4, 64), blk, 0, stream>>>(Hb, F2t + (size_t)l * FF_ * D_,
                                                       ff2_b + (size_t)l * D_, Fb, D_, FF_, 0);
            add_ln<<<M_, blk, 0, stream>>>(io, Fb, ln2_g + l * D_, ln2_b + l * D_, io, iob, 1e-5f);
        }
    };

    layer(0, 1, Y, Yb, Yb, true);
    layer(1, 1, Y, Yb, Yb, true);
    layer(2, 1, X, Xb, Xb, false);
    layer(3, 0, X, Xb, Yb, true);
    layer(4, 1, X, Xb, Xb, false);
    layer(5, 0, X, Xb, Yb, true);
}

// Round 6
// 1929.279 us; speedup vs baseline: 9.2838x; 1.1538x over previous
//
#include <hip/hip_runtime.h>
#include <math.h>

#define T_  1024
#define D_  512
#define H_  8
#define DK_ 64
#define FF_ 2048
#define BSZ 8
#define M_  (BSZ * T_)   // 8192 rows
#define TP_ (T_ + 4)     // padded rows per batch for causal conv

typedef unsigned short u16;
typedef unsigned int u32;
typedef __attribute__((ext_vector_type(8))) __bf16 bf16x8;
typedef __attribute__((ext_vector_type(4))) float f32x4;

__device__ __forceinline__ u16 f2bf(float f) {            // RNE f32 -> bf16 bits
    unsigned int u = __float_as_uint(f);
    u += 0x7fffu + ((u >> 16) & 1u);
    return (u16)(u >> 16);
}
__device__ __forceinline__ float bf2f(u16 b) {
    return __uint_as_float((unsigned int)b << 16);
}

__device__ __forceinline__ void gload16(const void* g, void* l) {
    // async global->LDS, 16B/lane; LDS dest = wave-uniform base + lane*16
    __builtin_amdgcn_global_load_lds(
        (const __attribute__((address_space(1))) void*)g,
        (__attribute__((address_space(3))) void*)l, 16, 0, 0);
}

// ======================= bf16 MFMA GEMM (m97 structure) =======================
// C[M][N] = A[M][K](bf16) * Bt[N][K]^T(bf16) + bias. 128x128 tile, 4 waves.
// mode 0: f32 out; 1: bf16 out + relu; 2: bf16 out; 3: per-head-transposed
// bf16 out Vt[((b*H+h)*DK+dl)*T + t]  (for PV B-operand).
__global__ void __launch_bounds__(256) gemm_mfma(
    const u16* __restrict__ A, const u16* __restrict__ Bt,
    const float* __restrict__ bias, void* __restrict__ Cout,
    int N, int K, int mode)
{
    __shared__ __align__(16) u16 As[128 * 32];
    __shared__ __align__(16) u16 Bs[128 * 32];
    int tid = threadIdx.x;
    int wid = tid >> 6, lane = tid & 63;
    int quad = lane >> 4, mrow = lane & 15;
    int m0 = blockIdx.y * 128, n0 = blockIdx.x * 128;
    int wr = (wid >> 1) * 64, wc = (wid & 1) * 64;

    const u16* Ap = A + (size_t)(m0 + (tid >> 2)) * K + (tid & 3) * 8;
    const u16* Bp = Bt + (size_t)(n0 + (tid >> 2)) * K + (tid & 3) * 8;
    char* lA = (char*)As + wid * 1024;
    char* lB = (char*)Bs + wid * 1024;

    f32x4 acc[4][4] = {};
    for (int k0 = 0; k0 < K; k0 += 32) {
        __syncthreads();
        gload16(Ap + k0, lA);
        gload16(Ap + (size_t)64 * K + k0, lA + 4096);
        gload16(Bp + k0, lB);
        gload16(Bp + (size_t)64 * K + k0, lB + 4096);
        asm volatile("s_waitcnt vmcnt(0)" ::: "memory");
        __syncthreads();
        bf16x8 af[4], bf[4];
#pragma unroll
        for (int t = 0; t < 4; ++t) {
            af[t] = *(const bf16x8*)&As[(wr + t * 16 + mrow) * 32 + quad * 8];
            bf[t] = *(const bf16x8*)&Bs[(wc + t * 16 + mrow) * 32 + quad * 8];
        }
#pragma unroll
        for (int rt = 0; rt < 4; ++rt)
#pragma unroll
            for (int ct = 0; ct < 4; ++ct)
                acc[rt][ct] = __builtin_amdgcn_mfma_f32_16x16x32_bf16(
                    af[rt], bf[ct], acc[rt][ct], 0, 0, 0);
    }

#pragma unroll
    for (int ct = 0; ct < 4; ++ct) {
        int col = n0 + wc + ct * 16 + mrow;
        float bv = bias ? bias[col] : 0.f;
#pragma unroll
        for (int rt = 0; rt < 4; ++rt) {
            int rowb = m0 + wr + rt * 16 + quad * 4;
            if (mode == 0) {
                float* C = (float*)Cout;
#pragma unroll
                for (int e = 0; e < 4; ++e)
                    C[(size_t)(rowb + e) * N + col] = acc[rt][ct][e] + bv;
            } else if (mode == 1) {
                u16* C = (u16*)Cout;
#pragma unroll
                for (int e = 0; e < 4; ++e)
                    C[(size_t)(rowb + e) * N + col] = f2bf(fmaxf(acc[rt][ct][e] + bv, 0.f));
            } else if (mode == 2) {
                u16* C = (u16*)Cout;
#pragma unroll
                for (int e = 0; e < 4; ++e)
                    C[(size_t)(rowb + e) * N + col] = f2bf(acc[rt][ct][e] + bv);
            } else {
                u16* C = (u16*)Cout;
                int h = col >> 6, dl = col & 63;
#pragma unroll
                for (int e = 0; e < 4; ++e) {
                    int row = rowb + e;
                    int b = row >> 10, t = row & (T_ - 1);
                    C[(((size_t)(b * H_ + h) * DK_ + dl) << 10) + t] =
                        f2bf(acc[rt][ct][e] + bv);
                }
            }
        }
    }
}

// ======================= causal conv1d: 5 shifted MFMA passes =======================
__global__ void __launch_bounds__(256) conv_mfma(
    const u16* __restrict__ Xp, const u16* __restrict__ W5t, float* __restrict__ C)
{
    __shared__ __align__(16) u16 As[128 * 32];
    __shared__ __align__(16) u16 Bs[128 * 32];
    int tid = threadIdx.x;
    int wid = tid >> 6, lane = tid & 63;
    int quad = lane >> 4, mrow = lane & 15;
    int m0 = blockIdx.y * 128, n0 = blockIdx.x * 128;
    int wr = (wid >> 1) * 64, wc = (wid & 1) * 64;
    int b = m0 >> 10, tloc = m0 & (T_ - 1);

    const u16* Ap0 = Xp + (size_t)(b * TP_ + tloc + (tid >> 2)) * D_ + (tid & 3) * 8;
    const u16* Bp0 = W5t + (size_t)(n0 + (tid >> 2)) * D_ + (tid & 3) * 8;
    char* lA = (char*)As + wid * 1024;
    char* lB = (char*)Bs + wid * 1024;

    f32x4 acc[4][4] = {};
    for (int ks = 0; ks < 5; ++ks) {
        const u16* Ap = Ap0 + ks * D_;
        const u16* Bp = Bp0 + (size_t)ks * D_ * D_;
        for (int k0 = 0; k0 < D_; k0 += 32) {
            __syncthreads();
            gload16(Ap + k0, lA);
            gload16(Ap + (size_t)64 * D_ + k0, lA + 4096);
            gload16(Bp + k0, lB);
            gload16(Bp + (size_t)64 * D_ + k0, lB + 4096);
            asm volatile("s_waitcnt vmcnt(0)" ::: "memory");
            __syncthreads();
            bf16x8 af[4], bf[4];
#pragma unroll
            for (int t = 0; t < 4; ++t) {
                af[t] = *(const bf16x8*)&As[(wr + t * 16 + mrow) * 32 + quad * 8];
                bf[t] = *(const bf16x8*)&Bs[(wc + t * 16 + mrow) * 32 + quad * 8];
            }
#pragma unroll
            for (int rt = 0; rt < 4; ++rt)
#pragma unroll
                for (int ct = 0; ct < 4; ++ct)
                    acc[rt][ct] = __builtin_amdgcn_mfma_f32_16x16x32_bf16(
                        af[rt], bf[ct], acc[rt][ct], 0, 0, 0);
        }
    }
#pragma unroll
    for (int ct = 0; ct < 4; ++ct) {
        int col = n0 + wc + ct * 16 + mrow;
#pragma unroll
        for (int rt = 0; rt < 4; ++rt) {
            int row = m0 + wr + rt * 16 + quad * 4;
#pragma unroll
            for (int e = 0; e < 4; ++e)
                C[(size_t)(row + e) * D_ + col] = acc[rt][ct][e];
        }
    }
}

// ======================= QK^T MFMA: S[z][i][k] bf16, causal tiles =======================
__global__ void __launch_bounds__(256) qk_mfma(
    const u16* __restrict__ Qh, u16* __restrict__ S)
{
    int kt = blockIdx.x, it = blockIdx.y;
    if (kt > it) return;
    int z = blockIdx.z;
    int b = z >> 3, h = z & 7;
    __shared__ __align__(16) u16 As[64 * 32];
    __shared__ __align__(16) u16 Bs[64 * 32];
    int tid = threadIdx.x;
    int wid = tid >> 6, lane = tid & 63;
    int quad = lane >> 4, mrow = lane & 15;
    int wc = wid * 16;

    const u16* Ap = Qh + (size_t)(b * T_ + it * 64 + (tid >> 2)) * D_ + h * DK_ + (tid & 3) * 8;
    const u16* Bp = Qh + (size_t)(b * T_ + kt * 64 + (tid >> 2)) * D_ + h * DK_ + (tid & 3) * 8;
    char* lA = (char*)As + wid * 1024;
    char* lB = (char*)Bs + wid * 1024;

    f32x4 acc[4] = {};
#pragma unroll
    for (int k0 = 0; k0 < DK_; k0 += 32) {
        __syncthreads();
        gload16(Ap + k0, lA);
        gload16(Bp + k0, lB);
        asm volatile("s_waitcnt vmcnt(0)" ::: "memory");
        __syncthreads();
        bf16x8 af[4];
#pragma unroll
        for (int t = 0; t < 4; ++t)
            af[t] = *(const bf16x8*)&As[(t * 16 + mrow) * 32 + quad * 8];
        bf16x8 bf = *(const bf16x8*)&Bs[(wc + mrow) * 32 + quad * 8];
#pragma unroll
        for (int rt = 0; rt < 4; ++rt)
            acc[rt] = __builtin_amdgcn_mfma_f32_16x16x32_bf16(af[rt], bf, acc[rt], 0, 0, 0);
    }
    int col = kt * 64 + wc + mrow;
#pragma unroll
    for (int rt = 0; rt < 4; ++rt) {
        int row = it * 64 + rt * 16 + quad * 4;
#pragma unroll
        for (int e = 0; e < 4; ++e)
            S[((size_t)z * T_ + row + e) * T_ + col] = f2bf(acc[rt][e] * 0.125f);
    }
}

// ======================= per-row decay + double softmax, one WAVE per row ==========
// 2 elements/lane: k = c*128 + 2*lane + {0,1}. Unrolled compile-time loops with
// wave-uniform break keep arrays in VGPRs (dynamic-bound loops spill to scratch).
// Masked entries ride through as -1e30 (exp underflows to exact 0 — no cndmasks).
__global__ void __launch_bounds__(256) decay_rows(
    u16* __restrict__ S, const float* __restrict__ gam_l, int mtype)
{
    int tid = threadIdx.x;
    int wv = tid >> 6, lane = tid & 63;
    int i = blockIdx.x * 4 + wv;
    int z = blockIdx.y;
    int h = z & 7;
    u16* row = S + ((size_t)z * T_ + i) * T_;
    int kmax = (mtype == 0) ? (i - 1) : i;

    if (kmax < 0) {                     // mtype==0, i==0 (zero_pad row); PV reads k<64
        row[lane] = 0;
        return;
    }
    int nc   = (kmax >> 7) + 1;         // active 128-wide chunks (<= 8)
    int wend = (((i >> 6) + 1) * 64 + 127) >> 7;  // chunks PV reads (zero-fill to here)

    float s0[8], s1[8], p0[8], p1[8];
    int base = lane * 2;

    // ---- load + row max ----
    float mx = -1e30f;
#pragma unroll
    for (int c = 0; c < 8; ++c) {
        if (c >= nc) break;
        int k = c * 128 + base;
        u32 v = *(const u32*)(row + k);
        float a = __uint_as_float(v << 16);
        float b = __uint_as_float(v & 0xffff0000u);
        a = (k     <= kmax) ? a : -1e30f;
        b = (k + 1 <= kmax) ? b : -1e30f;
        s0[c] = a; s1[c] = b;
        mx = fmaxf(mx, fmaxf(a, b));
    }
#pragma unroll
    for (int o = 32; o > 0; o >>= 1) mx = fmaxf(mx, __shfl_xor(mx, o, 64));

    // ---- softmax #1 (unnormalized; masked -> exp underflow 0) ----
    float tot = 0.f;
#pragma unroll
    for (int c = 0; c < 8; ++c) {
        if (c >= nc) break;
        float e0 = __expf(s0[c] - mx);
        float e1 = __expf(s1[c] - mx);
        p0[c] = e0; p1[c] = e1;
        tot += e0 + e1;
    }
#pragma unroll
    for (int o = 32; o > 0; o >>= 1) tot += __shfl_xor(tot, o, 64);
    float inv1 = 1.f / tot;

    // ---- pair-scan cumsum + distance effect ----
    float gam = -log1pf(__expf(gam_l[h]));
    float fi = (float)i;
    float kf = (float)base;
    float running = 0.f;
#pragma unroll
    for (int c = 0; c < 8; ++c) {
        if (c >= nc) break;
        float pair = p0[c] + p1[c];
        float sc = pair;
#pragma unroll
        for (int o = 1; o < 64; o <<= 1) {
            float y = __shfl_up(sc, o, 64);
            if (lane >= o) sc += y;
        }
        float excl = running + sc - pair;
        running += __shfl(sc, 63, 64);
        float incl0 = excl + p0[c];
        float incl1 = incl0 + p1[c];
        float rem0 = fmaxf((tot - incl0) * inv1, 0.f);
        float rem1 = fmaxf((tot - incl1) * inv1, 0.f);
        float pos0 = fabsf(kf - fi);
        float pos1 = fabsf(kf + 1.f - fi);
        float ef0 = fminf(fmaxf(__expf(sqrtf(rem0 * pos0) * gam), 1e-5f), 1e5f);
        float ef1 = fminf(fmaxf(__expf(sqrtf(rem1 * pos1) * gam), 1e-5f), 1e5f);
        s0[c] *= ef0;                   // masked: -1e30*eff <= -1e25, still excluded
        s1[c] *= ef1;
        kf += 128.f;
    }

    // ---- softmax #2 ----
    float mx2 = -1e30f;
#pragma unroll
    for (int c = 0; c < 8; ++c) {
        if (c >= nc) break;
        mx2 = fmaxf(mx2, fmaxf(s0[c], s1[c]));
    }
#pragma unroll
    for (int o = 32; o > 0; o >>= 1) mx2 = fmaxf(mx2, __shfl_xor(mx2, o, 64));
    float tot2 = 0.f;
#pragma unroll
    for (int c = 0; c < 8; ++c) {
        if (c >= nc) break;
        float e0 = __expf(s0[c] - mx2);
        float e1 = __expf(s1[c] - mx2);
        p0[c] = e0; p1[c] = e1;
        tot2 += e0 + e1;
    }
#pragma unroll
    for (int o = 32; o > 0; o >>= 1) tot2 += __shfl_xor(tot2, o, 64);
    float inv2 = 1.f / tot2;

    // ---- write P (packed 2xbf16), zero-fill tail chunks PV reads ----
#pragma unroll
    for (int c = 0; c < 8; ++c) {
        if (c >= nc) break;
        u32 o = (u32)f2bf(p0[c] * inv2) | ((u32)f2bf(p1[c] * inv2) << 16);
        *(u32*)(row + c * 128 + base) = o;
    }
#pragma unroll
    for (int c = 0; c < 8; ++c) {
        if (c < nc) continue;
        if (c >= wend) break;
        *(u32*)(row + c * 128 + base) = 0u;
    }
}

// ======================= PV MFMA: O = P(bf16) x V, causal K-bound =======================
__global__ void __launch_bounds__(256) pv_mfma(
    const u16* __restrict__ P, const u16* __restrict__ Vt,
    u16* __restrict__ O)
{
    int mt = blockIdx.x;
    int z = blockIdx.y;
    int b = z >> 3, h = z & 7;
    __shared__ __align__(16) u16 As[64 * 32];
    __shared__ __align__(16) u16 Bs[64 * 32];
    int tid = threadIdx.x;
    int wid = tid >> 6, lane = tid & 63;
    int quad = lane >> 4, mrow = lane & 15;
    int wc = wid * 16;

    const u16* Ap = P + ((size_t)z * T_ + mt * 64 + (tid >> 2)) * T_ + (tid & 3) * 8;
    const u16* Bp = Vt + ((size_t)z * DK_ + (tid >> 2)) * T_ + (tid & 3) * 8;
    char* lA = (char*)As + wid * 1024;
    char* lB = (char*)Bs + wid * 1024;

    int kend = (mt + 1) * 64;
    f32x4 acc[4] = {};
    for (int k0 = 0; k0 < kend; k0 += 32) {
        __syncthreads();
        gload16(Ap + k0, lA);
        gload16(Bp + k0, lB);
        asm volatile("s_waitcnt vmcnt(0)" ::: "memory");
        __syncthreads();
        bf16x8 af[4];
#pragma unroll
        for (int t = 0; t < 4; ++t)
            af[t] = *(const bf16x8*)&As[(t * 16 + mrow) * 32 + quad * 8];
        bf16x8 bf = *(const bf16x8*)&Bs[(wc + mrow) * 32 + quad * 8];
#pragma unroll
        for (int rt = 0; rt < 4; ++rt)
            acc[rt] = __builtin_amdgcn_mfma_f32_16x16x32_bf16(af[rt], bf, acc[rt], 0, 0, 0);
    }
    int col = h * DK_ + wc + mrow;
#pragma unroll
    for (int rt = 0; rt < 4; ++rt) {
        int row = b * T_ + mt * 64 + rt * 16 + quad * 4;
#pragma unroll
        for (int e = 0; e < 4; ++e)
            O[(size_t)(row + e) * D_ + col] = f2bf(acc[rt][e]);
    }
}

// ======================= prep kernels =======================
__global__ void __launch_bounds__(256) transpose_bf16(
    const float* __restrict__ W, u16* __restrict__ Wt, int K, int N)
{
    __shared__ float tile[32][33];
    size_t base = (size_t)blockIdx.z * K * N;
    W += base; Wt += base;
    int k0 = blockIdx.y * 32, n0 = blockIdx.x * 32;
    int r = threadIdx.x >> 3, c = (threadIdx.x & 7) * 4;
    float4 v = *(const float4*)(W + (size_t)(k0 + r) * N + n0 + c);
    tile[r][c] = v.x; tile[r][c + 1] = v.y; tile[r][c + 2] = v.z; tile[r][c + 3] = v.w;
    __syncthreads();
    ushort4 o;
    o.x = f2bf(tile[c + 0][r]); o.y = f2bf(tile[c + 1][r]);
    o.z = f2bf(tile[c + 2][r]); o.w = f2bf(tile[c + 3][r]);
    *(ushort4*)(Wt + (size_t)(n0 + r) * K + k0 + c) = o;
}

__global__ void w5_gather(const float* __restrict__ cw, u16* __restrict__ W5t)
{
    int idx = blockIdx.x * 256 + threadIdx.x;
    if (idx >= 5 * D_ * D_) return;
    int ks = idx / (D_ * D_);
    int rem = idx - ks * (D_ * D_);
    int o = rem >> 9, i = rem & (D_ - 1);
    W5t[idx] = f2bf(cw[((size_t)o * D_ + i) * 5 + ks]);
}

__global__ void cast_pad(const float* __restrict__ x, const float* __restrict__ y,
                         u16* __restrict__ Xp, u16* __restrict__ Yp)
{
    int idx = blockIdx.x * 256 + threadIdx.x;
    if (idx >= BSZ * TP_ * D_) return;
    int d = idx & (D_ - 1);
    int rowp = idx >> 9;
    int b = rowp / TP_;
    int t = rowp - b * TP_;
    u16 vx = 0, vy = 0;
    if (t >= 4) {
        size_t src = ((size_t)(b * T_ + t - 4) << 9) + d;
        vx = f2bf(x[src]); vy = f2bf(y[src]);
    }
    Xp[idx] = vx; Yp[idx] = vy;
}

// ======================= smooth pointwise + LayerNorm (eps=1e-12) =======================
__global__ void __launch_bounds__(256) smooth_ln(
    const float* __restrict__ x, const float* __restrict__ trend,
    const float* __restrict__ conv_b, const float* __restrict__ sqrt_beta,
    const float* __restrict__ g, const float* __restrict__ bb,
    float* __restrict__ out, u16* __restrict__ outb)
{
    __shared__ float s_red[8];
    int row = blockIdx.x, tid = threadIdx.x;
    int lane = tid & 63, wid = tid >> 6;
    float2 xv = ((const float2*)(x + (size_t)row * D_))[tid];
    float2 tv = ((const float2*)(trend + (size_t)row * D_))[tid];
    float2 cb = ((const float2*)conv_b)[tid];
    float2 sb = ((const float2*)sqrt_beta)[tid];
    float t0 = tv.x + cb.x, t1 = tv.y + cb.y;
    float v0 = t0 + sb.x * sb.x * (xv.x - t0) + xv.x;
    float v1 = t1 + sb.y * sb.y * (xv.y - t1) + xv.y;
    float s = v0 + v1, sq = v0 * v0 + v1 * v1;
    for (int o = 32; o > 0; o >>= 1) { s += __shfl_xor(s, o, 64); sq += __shfl_xor(sq, o, 64); }
    if (lane == 0) { s_red[wid] = s; s_red[4 + wid] = sq; }
    __syncthreads();
    s = s_red[0] + s_red[1] + s_red[2] + s_red[3];
    sq = s_red[4] + s_red[5] + s_red[6] + s_red[7];
    float mean = s * (1.f / D_);
    float var = sq * (1.f / D_) - mean * mean;
    if (var < 0.f) var = 0.f;
    float rstd = rsqrtf(var + 1e-12f);
    float2 gv = ((const float2*)g)[tid];
    float2 bv = ((const float2*)bb)[tid];
    float2 o2;
    o2.x = gv.x * (v0 - mean) * rstd + bv.x;
    o2.y = gv.y * (v1 - mean) * rstd + bv.y;
    ((float2*)(out + (size_t)row * D_))[tid] = o2;
    ushort2 ob; ob.x = f2bf(o2.x); ob.y = f2bf(o2.y);
    ((ushort2*)(outb + (size_t)row * D_))[tid] = ob;
}

// ======================= residual add + LayerNorm (f32 + bf16 out) =======================
__global__ void __launch_bounds__(256) add_ln(
    const float* __restrict__ a, const float* __restrict__ c,
    const float* __restrict__ g, const float* __restrict__ bb,
    float* __restrict__ out, u16* __restrict__ outb, float eps)
{
    __shared__ float s_red[8];
    int row = blockIdx.x, tid = threadIdx.x;
    int lane = tid & 63, wid = tid >> 6;
    float2 av = ((const float2*)(a + (size_t)row * D_))[tid];
    float2 cv = ((const float2*)(c + (size_t)row * D_))[tid];
    float v0 = av.x + cv.x;
    float v1 = av.y + cv.y;
    float s = v0 + v1, sq = v0 * v0 + v1 * v1;
    for (int o = 32; o > 0; o >>= 1) { s += __shfl_xor(s, o, 64); sq += __shfl_xor(sq, o, 64); }
    if (lane == 0) { s_red[wid] = s; s_red[4 + wid] = sq; }
    __syncthreads();
    s = s_red[0] + s_red[1] + s_red[2] + s_red[3];
    sq = s_red[4] + s_red[5] + s_red[6] + s_red[7];
    float mean = s * (1.f / D_);
    float var = sq * (1.f / D_) - mean * mean;
    if (var < 0.f) var = 0.f;
    float rstd = rsqrtf(var + eps);
    float2 gv = ((const float2*)g)[tid];
    float2 bv = ((const float2*)bb)[tid];
    float2 o2;
    o2.x = gv.x * (v0 - mean) * rstd + bv.x;
    o2.y = gv.y * (v1 - mean) * rstd + bv.y;
    ((float2*)(out + (size_t)row * D_))[tid] = o2;
    ushort2 ob; ob.x = f2bf(o2.x); ob.y = f2bf(o2.y);
    ((ushort2*)(outb + (size_t)row * D_))[tid] = ob;
}

// ======================= launch =======================
extern "C" void kernel_launch(void* const* d_in, const int* in_sizes, int n_in,
                              void* d_out, int out_size, void* d_ws, size_t ws_size,
                              hipStream_t stream)
{
    const float* q_embed   = (const float*)d_in[0];
    const float* qa_embed  = (const float*)d_in[1];
    const float* conv_w    = (const float*)d_in[3];
    const float* conv_b    = (const float*)d_in[4];
    const float* sqrt_beta = (const float*)d_in[5];
    const float* sm_g      = (const float*)d_in[6];
    const float* sm_b      = (const float*)d_in[7];
    const float* k_w       = (const float*)d_in[8];
    const float* k_b       = (const float*)d_in[9];
    const float* v_w       = (const float*)d_in[10];
    const float* v_b       = (const float*)d_in[11];
    const float* out_w     = (const float*)d_in[12];
    const float* out_b     = (const float*)d_in[13];
    const float* gammas    = (const float*)d_in[14];
    const float* ln1_g     = (const float*)d_in[15];
    const float* ln1_b     = (const float*)d_in[16];
    const float* ff1_w     = (const float*)d_in[17];
    const float* ff1_b     = (const float*)d_in[18];
    const float* ff2_w     = (const float*)d_in[19];
    const float* ff2_b     = (const float*)d_in[20];
    const float* ln2_g     = (const float*)d_in[21];
    const float* ln2_b     = (const float*)d_in[22];

    const size_t NT = (size_t)M_ * D_;
    float* X = (float*)d_out;
    char* w = (char*)d_ws;
    float* Y  = (float*)w; w += NT * 4;          // 16 MB
    float* Fb = (float*)w; w += NT * 4;          // 16 MB
    u16* Sb = (u16*)w;                           // scores/P bf16: 128 MB
    u16* Hb = Sb;                                // aliases: ffn hidden bf16 (32 MB)
    u16* Xpad = Sb;                              // aliases: prep buffers
    u16* Ypad = Xpad + (size_t)BSZ * TP_ * D_;
    u16* W5t  = Ypad + (size_t)BSZ * TP_ * D_;
    w += (size_t)BSZ * H_ * T_ * T_ * 2;
    u16* Xb  = (u16*)w; w += NT * 2;
    u16* Yb  = (u16*)w; w += NT * 2;
    u16* Cb  = (u16*)w; w += NT * 2;
    u16* Qh  = (u16*)w; w += NT * 2;
    u16* Vt  = (u16*)w; w += NT * 2;
    u16* KWt = (u16*)w; w += (size_t)6 * D_ * D_ * 2;
    u16* VWt = (u16*)w; w += (size_t)6 * D_ * D_ * 2;
    u16* OWt = (u16*)w; w += (size_t)6 * D_ * D_ * 2;
    u16* F1t = (u16*)w; w += (size_t)6 * D_ * FF_ * 2;
    u16* F2t = (u16*)w; w += (size_t)6 * FF_ * D_ * 2;

    dim3 blk(256);

    // ---- prep ----
    cast_pad<<<(BSZ * TP_ * D_ + 255) / 256, blk, 0, stream>>>(q_embed, qa_embed, Xpad, Ypad);
    w5_gather<<<(5 * D_ * D_ + 255) / 256, blk, 0, stream>>>(conv_w, W5t);
    transpose_bf16<<<dim3(D_ / 32, D_ / 32, 6), blk, 0, stream>>>(k_w, KWt, D_, D_);
    transpose_bf16<<<dim3(D_ / 32, D_ / 32, 6), blk, 0, stream>>>(v_w, VWt, D_, D_);
    transpose_bf16<<<dim3(D_ / 32, D_ / 32, 6), blk, 0, stream>>>(out_w, OWt, D_, D_);
    transpose_bf16<<<dim3(FF_ / 32, D_ / 32, 6), blk, 0, stream>>>(ff1_w, F1t, D_, FF_);
    transpose_bf16<<<dim3(D_ / 32, FF_ / 32, 6), blk, 0, stream>>>(ff2_w, F2t, FF_, D_);

    // ---- smooth(x), smooth(y) ----
    conv_mfma<<<dim3(4, 64), blk, 0, stream>>>(Xpad, W5t, Fb);
    smooth_ln<<<M_, blk, 0, stream>>>(q_embed, Fb, conv_b, sqrt_beta, sm_g, sm_b, X, Xb);
    conv_mfma<<<dim3(4, 64), blk, 0, stream>>>(Ypad, W5t, Fb);
    smooth_ln<<<M_, blk, 0, stream>>>(qa_embed, Fb, conv_b, sqrt_beta, sm_g, sm_b, Y, Yb);

    auto layer = [&](int l, int mtype, float* io, u16* iob, const u16* vinb, bool ffn) {
        gemm_mfma<<<dim3(4, 64), blk, 0, stream>>>(iob, KWt + (size_t)l * D_ * D_,
                                                   k_b + (size_t)l * D_, Qh, D_, D_, 2);
        gemm_mfma<<<dim3(4, 64), blk, 0, stream>>>(vinb, VWt + (size_t)l * D_ * D_,
                                                   v_b + (size_t)l * D_, Vt, D_, D_, 3);
        qk_mfma<<<dim3(16, 16, 64), blk, 0, stream>>>(Qh, Sb);
        decay_rows<<<dim3(T_ / 4, 64), blk, 0, stream>>>(Sb, gammas + l * H_, mtype);
        pv_mfma<<<dim3(16, 64), blk, 0, stream>>>(Sb, Vt, Cb);
        gemm_mfma<<<dim3(4, 64), blk, 0, stream>>>(Cb, OWt + (size_t)l * D_ * D_,
                                                   out_b + (size_t)l * D_, Fb, D_, D_, 0);
        add_ln<<<M_, blk, 0, stream>>>(io, Fb, ln1_g + l * D_, ln1_b + l * D_, io, iob, 1e-5f);
        if (ffn) {
            gemm_mfma<<<dim3(16, 64), blk, 0, stream>>>(iob, F1t + (size_t)l * D_ * FF_,
                                                        ff1_b + (size_t)l * FF_, Hb, FF_, D_, 1);
            gemm_mfma<<<dim3(4, 64), blk, 0, stream>>>(Hb, F2t + (size_t)l * FF_ * D_,
                                                       ff2_b + (size_t)l * D_, Fb, D_, FF_, 0);
            add_ln<<<M_, blk, 0, stream>>>(io, Fb, ln2_g + l * D_, ln2_b + l * D_, io, iob, 1e-5f);
        }
    };

    layer(0, 1, Y, Yb, Yb, true);
    layer(1, 1, Y, Yb, Yb, true);
    layer(2, 1, X, Xb, Xb, false);
    layer(3, 0, X, Xb, Yb, true);
    layer(4, 1, X, Xb, Xb, false);
    layer(5, 0, X, Xb, Yb, true);
}